// Round 2
// baseline (2003.446 us; speedup 1.0000x reference)
//
#include <hip/hip_runtime.h>
#include <math.h>

// Problem constants (fixed by setup_inputs)
#define B_   4
#define N_   4096
#define E_   1024
#define H_   16
#define BN_  (B_*N_)
#define BH_  (B_*H_)
#define SPLITK 8

// favorp constants
#define NRM_C   0.35355339059327373f   // 64^-0.25
#define DIAG_C  0.0625f                // 0.5 * NRM^2
#define RATIO_C 0.125f                 // 64^-0.5
#define EPSF    1e-4f
#define EPSD    0.01f

__device__ __forceinline__ void atomicMaxF(float* addr, float v) {
    // order-independent, deterministic float max
    if (v >= 0.f) atomicMax((int*)addr, __float_as_int(v));
    else          atomicMin((unsigned int*)addr, __float_as_uint(v));
}

__global__ void init_stab(float* stab) {
    if (threadIdx.x < BH_) stab[threadIdx.x] = -INFINITY;
}

// ---------------- Linear: Y = X @ W^T + bias ----------------
// IN_MODE 0: logical row r=b*N+n reads input[(n*B+b)*E + e]   ([N,B,E] input)
// IN_MODE 1: X row-major [BN,E]
// OUT_MODE 0: Y[r*E+f]   ([B,N,E])      OUT_MODE 1: Y[(n*B+b)*E+f]  ([N,B,E])
template<int IN_MODE, int OUT_MODE>
__global__ __launch_bounds__(256) void lin_gemm(const float* __restrict__ X,
                                                const float* __restrict__ W,
                                                const float* __restrict__ bias,
                                                float* __restrict__ Y)
{
    __shared__ float As[16][68];   // [k][r], row stride 272B (16B-aligned)
    __shared__ float Ws[16][68];   // [k][f]
    const int row0 = blockIdx.x * 64;
    const int col0 = blockIdx.y * 64;
    const int t  = threadIdx.x;
    const int lr = t >> 2;          // 0..63
    const int lk = (t & 3) * 4;     // 0,4,8,12
    const int ty = t >> 4, tx = t & 15;

    long arow;
    {
        int r = row0 + lr;
        if (IN_MODE == 0) { int b = r >> 12, n = r & (N_ - 1); arow = (long)(n * B_ + b) * E_; }
        else              { arow = (long)r * E_; }
    }
    const long wrow = (long)(col0 + lr) * E_;

    float acc[4][4] = {};
    for (int e0 = 0; e0 < E_; e0 += 16) {
        float4 av = *(const float4*)(X + arow + e0 + lk);
        float4 wv = *(const float4*)(W + wrow + e0 + lk);
        As[lk+0][lr] = av.x; As[lk+1][lr] = av.y; As[lk+2][lr] = av.z; As[lk+3][lr] = av.w;
        Ws[lk+0][lr] = wv.x; Ws[lk+1][lr] = wv.y; Ws[lk+2][lr] = wv.z; Ws[lk+3][lr] = wv.w;
        __syncthreads();
#pragma unroll
        for (int k = 0; k < 16; ++k) {
            float4 a = *(const float4*)&As[k][ty*4];
            float4 w = *(const float4*)&Ws[k][tx*4];
            float a_[4] = {a.x,a.y,a.z,a.w};
            float w_[4] = {w.x,w.y,w.z,w.w};
#pragma unroll
            for (int i = 0; i < 4; ++i)
#pragma unroll
                for (int j = 0; j < 4; ++j)
                    acc[i][j] = fmaf(a_[i], w_[j], acc[i][j]);
        }
        __syncthreads();
    }
    float4 bv = *(const float4*)(bias + col0 + tx*4);
    float b_[4] = {bv.x,bv.y,bv.z,bv.w};
#pragma unroll
    for (int i = 0; i < 4; ++i) {
        int r = row0 + ty*4 + i;
        float4 o;
        o.x = acc[i][0] + b_[0]; o.y = acc[i][1] + b_[1];
        o.z = acc[i][2] + b_[2]; o.w = acc[i][3] + b_[3];
        long off;
        if (OUT_MODE == 0) off = (long)r * E_ + col0 + tx*4;
        else { int b = r >> 12, n = r & (N_ - 1); off = (long)(n * B_ + b) * E_ + col0 + tx*4; }
        *(float4*)(Y + off) = o;
    }
}

// ---------------- favorp dash (IN-PLACE over [B,N,E] head-split buffer) ----------------
// IS_QUERY=1: X <- ratio*exp(dash - diag - rowmax(dash)) + eps   (q_prime)
// IS_QUERY=0: X <- dash - diag (log-space), and stab[bh] = atomic max(dash)
template<int IS_QUERY>
__global__ __launch_bounds__(256) void favorp_dash(float* __restrict__ Xh,       // [B,N,E] in-out
                                                   const float* __restrict__ proj, // [H,64,64]
                                                   float* __restrict__ stab)     // [BH]
{
    __shared__ float Xs[64][68];     // [d][r]
    __shared__ float Ps[64][68];     // [d][m]
    __shared__ float diag[64];
    __shared__ float red4[4];
    __shared__ float rowred[64][17]; // query row-max staging
    const int bh = blockIdx.x, b = bh >> 4, h = bh & 15;
    const int n0 = blockIdx.y * 64;
    const int t = threadIdx.x;
    const int r = t >> 2, c0 = (t & 3) * 16;
    const int ty = t >> 4, tx = t & 15;

    const float* xrow = Xh + (long)(b * N_ + n0 + r) * E_ + h * 64;
    const float* prow = proj + (long)(h * 64 + r) * 64;
#pragma unroll
    for (int c = 0; c < 4; ++c) {
        float4 v = *(const float4*)(xrow + c0 + c*4);
        Xs[c0+c*4+0][r] = v.x; Xs[c0+c*4+1][r] = v.y; Xs[c0+c*4+2][r] = v.z; Xs[c0+c*4+3][r] = v.w;
        float4 p = *(const float4*)(prow + c0 + c*4);
        Ps[c0+c*4+0][r] = p.x; Ps[c0+c*4+1][r] = p.y; Ps[c0+c*4+2][r] = p.z; Ps[c0+c*4+3][r] = p.w;
    }
    __syncthreads();
    if (t < 64) {
        float s = 0.f;
#pragma unroll 16
        for (int d = 0; d < 64; ++d) { float x = Xs[d][t]; s = fmaf(x, x, s); }
        diag[t] = s * DIAG_C;
    }
    __syncthreads();

    float acc[4][4] = {};
#pragma unroll 16
    for (int d = 0; d < 64; ++d) {
        float4 a = *(const float4*)&Xs[d][ty*4];
        float4 p = *(const float4*)&Ps[d][tx*4];
        float a_[4] = {a.x,a.y,a.z,a.w};
        float p_[4] = {p.x,p.y,p.z,p.w};
#pragma unroll
        for (int i = 0; i < 4; ++i)
#pragma unroll
            for (int j = 0; j < 4; ++j)
                acc[i][j] = fmaf(a_[i], p_[j], acc[i][j]);
    }
    float dash[4][4];
#pragma unroll
    for (int i = 0; i < 4; ++i)
#pragma unroll
        for (int j = 0; j < 4; ++j) dash[i][j] = acc[i][j] * NRM_C;

    if (IS_QUERY) {
#pragma unroll
        for (int i = 0; i < 4; ++i) {
            float m = fmaxf(fmaxf(dash[i][0], dash[i][1]), fmaxf(dash[i][2], dash[i][3]));
            rowred[ty*4+i][tx] = m;
        }
        __syncthreads();
#pragma unroll
        for (int i = 0; i < 4; ++i) {
            int row = ty*4 + i;
            float m = rowred[row][0];
#pragma unroll
            for (int jj = 1; jj < 16; ++jj) m = fmaxf(m, rowred[row][jj]);
            float dg = diag[row];
            float4 o;
            o.x = RATIO_C * expf(dash[i][0] - dg - m) + EPSF;
            o.y = RATIO_C * expf(dash[i][1] - dg - m) + EPSF;
            o.z = RATIO_C * expf(dash[i][2] - dg - m) + EPSF;
            o.w = RATIO_C * expf(dash[i][3] - dg - m) + EPSF;
            *(float4*)(Xh + (long)(b * N_ + n0 + row) * E_ + h * 64 + tx*4) = o;
        }
    } else {
        float lmax = dash[0][0];
#pragma unroll
        for (int i = 0; i < 4; ++i)
#pragma unroll
            for (int j = 0; j < 4; ++j) lmax = fmaxf(lmax, dash[i][j]);
#pragma unroll
        for (int i = 0; i < 4; ++i) {
            int row = ty*4 + i;
            float dg = diag[row];
            float4 o = { dash[i][0]-dg, dash[i][1]-dg, dash[i][2]-dg, dash[i][3]-dg };
            *(float4*)(Xh + (long)(b * N_ + n0 + row) * E_ + h * 64 + tx*4) = o;
        }
#pragma unroll
        for (int off = 32; off > 0; off >>= 1) lmax = fmaxf(lmax, __shfl_down(lmax, off));
        if ((t & 63) == 0) red4[t >> 6] = lmax;
        __syncthreads();
        if (t == 0)
            atomicMaxF(&stab[bh], fmaxf(fmaxf(red4[0], red4[1]), fmaxf(red4[2], red4[3])));
    }
}

// ---------------- kv partials: kv[m][d] = sum_n k'[n,m] v[n,d] ; ksum[m] = sum_n k'[n,m]
// T1 (k log-space) and V both in [B,N,E] head-split layout.
__global__ __launch_bounds__(256) void kv_partial(const float* __restrict__ T1,  // [B,N,E]
                                                  const float* __restrict__ V,   // [B,N,E]
                                                  const float* __restrict__ stab,
                                                  float* __restrict__ kvp,       // [SPLITK,BH,64,64]
                                                  float* __restrict__ ksump)     // [SPLITK,BH,64]
{
    __shared__ float KPs[16][68];
    __shared__ float Vs[16][68];
    const int bh = blockIdx.x, chunk = blockIdx.y;
    const int b = bh >> 4, h = bh & 15;
    const int t = threadIdx.x;
    const int lr = t >> 4, lm = (t & 15) * 4;
    const int ty = t >> 4, tx = t & 15;
    const float stb = stab[bh];
    float acc[4][4] = {};
    float ks = 0.f;
    const int nbeg = chunk * (N_ / SPLITK), nend = nbeg + (N_ / SPLITK);
    for (int n0 = nbeg; n0 < nend; n0 += 16) {
        long rowoff = (long)(b * N_ + n0 + lr) * E_ + h * 64 + lm;
        float4 tv = *(const float4*)(T1 + rowoff);
        float4 vv = *(const float4*)(V + rowoff);
        KPs[lr][lm+0] = RATIO_C * expf(tv.x - stb) + EPSF;
        KPs[lr][lm+1] = RATIO_C * expf(tv.y - stb) + EPSF;
        KPs[lr][lm+2] = RATIO_C * expf(tv.z - stb) + EPSF;
        KPs[lr][lm+3] = RATIO_C * expf(tv.w - stb) + EPSF;
        *(float4*)&Vs[lr][lm] = vv;
        __syncthreads();
        if (t < 64) {
#pragma unroll
            for (int rr = 0; rr < 16; ++rr) ks += KPs[rr][t];
        }
#pragma unroll
        for (int k = 0; k < 16; ++k) {
            float4 a = *(const float4*)&KPs[k][ty*4];
            float4 v4 = *(const float4*)&Vs[k][tx*4];
            float a_[4] = {a.x,a.y,a.z,a.w};
            float v_[4] = {v4.x,v4.y,v4.z,v4.w};
#pragma unroll
            for (int i = 0; i < 4; ++i)
#pragma unroll
                for (int j = 0; j < 4; ++j)
                    acc[i][j] = fmaf(a_[i], v_[j], acc[i][j]);
        }
        __syncthreads();
    }
    const long kvbase = ((long)chunk * BH_ + bh) * 4096;
#pragma unroll
    for (int i = 0; i < 4; ++i) {
        float4 o = {acc[i][0], acc[i][1], acc[i][2], acc[i][3]};
        *(float4*)(kvp + kvbase + (ty*4+i) * 64 + tx*4) = o;
    }
    if (t < 64) ksump[((long)chunk * BH_ + bh) * 64 + t] = ks;
}

__global__ __launch_bounds__(256) void kv_reduce(const float* __restrict__ kvp,
                                                 const float* __restrict__ ksump,
                                                 float* __restrict__ kv,
                                                 float* __restrict__ ksum)
{
    int idx = blockIdx.x * 256 + threadIdx.x;
    if (idx < BH_ * 4096) {
        float s = 0.f;
#pragma unroll
        for (int c = 0; c < SPLITK; ++c) s += kvp[(long)c * BH_ * 4096 + idx];
        kv[idx] = s;
    } else {
        int j = idx - BH_ * 4096;
        if (j < BH_ * 64) {
            float s = 0.f;
#pragma unroll
            for (int c = 0; c < SPLITK; ++c) s += ksump[(long)c * BH_ * 64 + j];
            ksum[j] = s;
        }
    }
}

// ---------------- qkv + normalize: attn[b,n,h*64+d] = (sum_m q'[n,m] kv[m,d]) / max(norm,eps)
// Qp in [B,N,E] head-split layout.
__global__ __launch_bounds__(256) void qkv_attn(const float* __restrict__ Qp,   // [B,N,E]
                                                const float* __restrict__ kvM,  // [BH,64,64]
                                                const float* __restrict__ ksum, // [BH,64]
                                                float* __restrict__ attn)       // [B,N,E]
{
    __shared__ float QPs[64][68];  // [m][r] (transposed)
    __shared__ float kvs[64][68];  // [m][d]
    __shared__ float ksums[64];
    __shared__ float rnorm[64];
    const int bh = blockIdx.x, b = bh >> 4, h = bh & 15;
    const int n0 = blockIdx.y * 64;
    const int t = threadIdx.x;
    const int r = t >> 2, c0 = (t & 3) * 16;
    const int ty = t >> 4, tx = t & 15;

#pragma unroll
    for (int c = 0; c < 4; ++c) {
        int idx = t * 16 + c * 4;
        float4 v = *(const float4*)(kvM + (long)bh * 4096 + idx);
        *(float4*)&kvs[idx >> 6][idx & 63] = v;
    }
    if (t < 64) ksums[t] = ksum[bh * 64 + t];
    const float* qrow = Qp + (long)(b * N_ + n0 + r) * E_ + h * 64;
#pragma unroll
    for (int c = 0; c < 4; ++c) {
        float4 v = *(const float4*)(qrow + c0 + c*4);
        QPs[c0+c*4+0][r] = v.x; QPs[c0+c*4+1][r] = v.y; QPs[c0+c*4+2][r] = v.z; QPs[c0+c*4+3][r] = v.w;
    }
    __syncthreads();
    if (t < 64) {
        float s = 0.f;
#pragma unroll 16
        for (int m = 0; m < 64; ++m) s = fmaf(QPs[m][t], ksums[m], s);
        rnorm[t] = 1.f / fmaxf(s, EPSD);
    }
    __syncthreads();
    float acc[4][4] = {};
#pragma unroll 16
    for (int m = 0; m < 64; ++m) {
        float4 a = *(const float4*)&QPs[m][ty*4];
        float4 v4 = *(const float4*)&kvs[m][tx*4];
        float a_[4] = {a.x,a.y,a.z,a.w};
        float v_[4] = {v4.x,v4.y,v4.z,v4.w};
#pragma unroll
        for (int i = 0; i < 4; ++i)
#pragma unroll
            for (int j = 0; j < 4; ++j)
                acc[i][j] = fmaf(a_[i], v_[j], acc[i][j]);
    }
#pragma unroll
    for (int i = 0; i < 4; ++i) {
        int row = ty*4 + i;
        float rn = rnorm[row];
        float4 o = {acc[i][0]*rn, acc[i][1]*rn, acc[i][2]*rn, acc[i][3]*rn};
        *(float4*)(attn + (long)(b * N_ + n0 + row) * E_ + h * 64 + tx*4) = o;
    }
}

extern "C" void kernel_launch(void* const* d_in, const int* in_sizes, int n_in,
                              void* d_out, int out_size, void* d_ws, size_t ws_size,
                              hipStream_t stream)
{
    const float* query = (const float*)d_in[0];
    const float* key   = (const float*)d_in[1];
    const float* value = (const float*)d_in[2];
    const float* Wq    = (const float*)d_in[3];
    const float* bq    = (const float*)d_in[4];
    const float* Wk    = (const float*)d_in[5];
    const float* bk    = (const float*)d_in[6];
    const float* Wv    = (const float*)d_in[7];
    const float* bv    = (const float*)d_in[8];
    const float* Wo    = (const float*)d_in[9];
    const float* bo    = (const float*)d_in[10];
    const float* proj  = (const float*)d_in[11];
    float* O = (float*)d_out;   // also used as scratch; fully rewritten at the end

    float* ws = (float*)d_ws;
    const size_t SZ = (size_t)BN_ * E_;      // 16.78M floats (67.1 MB)
    float* A     = ws;                        // V, later attn
    float* kvp   = ws + SZ;                   // [SPLITK,BH,64,64]   8.4 MB
    float* ksump = kvp + (size_t)SPLITK * BH_ * 4096;
    float* kvM   = ksump + (size_t)SPLITK * BH_ * 64;
    float* ksum  = kvM + (size_t)BH_ * 4096;
    float* stab  = ksum + (size_t)BH_ * 64;
    // total ws use: SZ + 2,396,224 floats  ~= 76.7 MB

    dim3 gGemm(BN_ / 64, E_ / 64);
    dim3 gF(BH_, N_ / 64);
    dim3 gKV(BH_, SPLITK);

    // 1) K = key @ Wk^T + bk  -> O (scratch, [B,N,E])
    lin_gemm<0,0><<<gGemm, 256, 0, stream>>>(key, Wk, bk, O);
    init_stab<<<1, 64, 0, stream>>>(stab);
    // 2) k log-space (dash - diag) in-place on O; stab[bh] = max(dash)
    favorp_dash<0><<<gF, 256, 0, stream>>>(O, proj, stab);
    // 3) V = value @ Wv^T + bv -> A
    lin_gemm<0,0><<<gGemm, 256, 0, stream>>>(value, Wv, bv, A);
    // 4) kv = k'^T v, ksum = k'^T 1   (split-K deterministic)
    kv_partial<<<gKV, 256, 0, stream>>>(O, A, stab, kvp, ksump);
    kv_reduce<<<(BH_ * 4096 + BH_ * 64) / 256, 256, 0, stream>>>(kvp, ksump, kvM, ksum);
    // 5) Q = query @ Wq^T + bq -> O (overwrites k log values)
    lin_gemm<0,0><<<gGemm, 256, 0, stream>>>(query, Wq, bq, O);
    // 6) q_prime in-place on O
    favorp_dash<1><<<gF, 256, 0, stream>>>(O, proj, stab);
    // 7) attn = (q' kv) / max(q' ksum, eps) -> A
    qkv_attn<<<gF, 256, 0, stream>>>(O, kvM, ksum, A);
    // 8) out = attn @ Wo^T + bo -> d_out ([N,B,E]), fully overwrites scratch
    lin_gemm<1,1><<<gGemm, 256, 0, stream>>>(A, Wo, bo, O);
}

// Round 3
// 667.002 us; speedup vs baseline: 3.0037x; 3.0037x over previous
//
#include <hip/hip_runtime.h>
#include <math.h>

// Problem constants (fixed by setup_inputs)
#define B_   4
#define N_   4096
#define E_   1024
#define H_   16
#define BN_  (B_*N_)
#define BH_  (B_*H_)
#define SPLITK 8

// favorp constants
#define NRM_C   0.35355339059327373f   // 64^-0.25
#define DIAG_C  0.0625f                // 0.5 * NRM^2
#define RATIO_C 0.125f                 // 64^-0.5
#define EPSF    1e-4f
#define EPSD    0.01f

typedef __attribute__((ext_vector_type(8))) short bf16x8;   // 8 bf16 in 4 VGPRs
typedef __attribute__((ext_vector_type(4))) float f32x4;

__device__ __forceinline__ unsigned short f32_to_bf16(float x) {
    unsigned int u = __float_as_uint(x);
    unsigned int r = (u + 0x7fffu + ((u >> 16) & 1u)) >> 16;   // RTN-even
    return (unsigned short)r;
}
__device__ __forceinline__ float bf16_to_f32(unsigned short h) {
    return __uint_as_float(((unsigned int)h) << 16);
}

__device__ __forceinline__ void atomicMaxF(float* addr, float v) {
    if (v >= 0.f) atomicMax((int*)addr, __float_as_int(v));
    else          atomicMin((unsigned int*)addr, __float_as_uint(v));
}

__global__ void init_stab(float* stab) {
    if (threadIdx.x < BH_) stab[threadIdx.x] = -INFINITY;
}

// ---------------- split-bf16 conversion ----------------
// Writes hi/lo bf16 in row-major [BN,E] (logical row r = b*N+n).
// IN_MODE 0: src is [N,B,E] (gather). IN_MODE 1: src is [rows,E] row-major.
template<int IN_MODE>
__global__ __launch_bounds__(256) void convert_split(const float* __restrict__ src,
                                                     unsigned short* __restrict__ hi,
                                                     unsigned short* __restrict__ lo,
                                                     int total4)
{
    int i = blockIdx.x * 256 + threadIdx.x;
    const int stride = gridDim.x * 256;
    for (; i < total4; i += stride) {
        long e4 = (long)i * 4;
        const float* p;
        if (IN_MODE == 0) {
            long r = e4 >> 10; int e = (int)(e4 & 1023);
            int b = (int)(r >> 12), n = (int)(r & 4095);
            p = src + (((long)(n * B_ + b)) << 10) + e;
        } else {
            p = src + e4;
        }
        float4 v = *(const float4*)p;
        ushort4 h, l;
        h.x = f32_to_bf16(v.x); l.x = f32_to_bf16(v.x - bf16_to_f32(h.x));
        h.y = f32_to_bf16(v.y); l.y = f32_to_bf16(v.y - bf16_to_f32(h.y));
        h.z = f32_to_bf16(v.z); l.z = f32_to_bf16(v.z - bf16_to_f32(h.z));
        h.w = f32_to_bf16(v.w); l.w = f32_to_bf16(v.w - bf16_to_f32(h.w));
        *(ushort4*)(hi + e4) = h;
        *(ushort4*)(lo + e4) = l;
    }
}

// ---------------- MFMA split-bf16 GEMM: Y = X @ W^T + bias ----------------
// A (X) hi/lo: [16384,1024] bf16 row-major. B (W) hi/lo: [1024,1024] bf16 row-major.
// 128x128 tile, BK=32, 4 waves (each 64x64), double-buffered LDS via global_load_lds,
// 16B-slot XOR swizzle (pre-swizzled global source, swizzled ds_read).
__device__ __forceinline__ void gl_lds16(const unsigned short* g, unsigned short* l) {
    __builtin_amdgcn_global_load_lds((const __attribute__((address_space(1))) void*)g,
                                     (__attribute__((address_space(3))) void*)l, 16, 0, 0);
}

template<int OUT_MODE>   // 0: Y[r*E+c]  ([B,N,E]);  1: Y[(n*B+b)*E+c]  ([N,B,E])
__global__ __launch_bounds__(256) void gemm_mfma(const unsigned short* __restrict__ Ahi,
                                                 const unsigned short* __restrict__ Alo,
                                                 const unsigned short* __restrict__ Bhi,
                                                 const unsigned short* __restrict__ Blo,
                                                 const float* __restrict__ bias,
                                                 float* __restrict__ Y)
{
    __shared__ __align__(16) unsigned short smem[2 * 4 * 4096];  // 2 buf x 4 tensors x 8KB
    const int t = threadIdx.x;
    const int w = t >> 6, lane = t & 63;
    const int row0 = blockIdx.x * 128, col0 = blockIdx.y * 128;
    const int wrow = (w >> 1) * 64, wcol = (w & 1) * 64;
    const int g = lane >> 4, rl = lane & 15;

    // staging addresses (per lane): row-in-tile = w*32 + lane/4 (+16 for 2nd inst),
    // source k-slot pre-swizzled: slot ^ (row&3); (w*32)&3 == 0 so row&3 == (lane>>2)&3
    const int sr = w * 32 + (lane >> 2);
    const int kswz = (((lane & 3) ^ ((lane >> 2) & 3)) << 3);
    const long aoff = (long)(row0 + sr) * E_ + kswz;
    const long boff = (long)(col0 + sr) * E_ + kswz;

    f32x4 acc[4][4];
#pragma unroll
    for (int m = 0; m < 4; ++m)
#pragma unroll
        for (int n = 0; n < 4; ++n) acc[m][n] = (f32x4){0.f, 0.f, 0.f, 0.f};

#define STAGE_STEP(KS, BUF)                                                          \
    {                                                                                \
        const int k0 = (KS) * 32;                                                    \
        unsigned short* d = smem + (BUF) * 16384 + w * 1024;                         \
        gl_lds16(Ahi + aoff + k0,             d);                                    \
        gl_lds16(Ahi + aoff + k0 + 16 * E_,   d + 512);                              \
        gl_lds16(Alo + aoff + k0,             d + 4096);                             \
        gl_lds16(Alo + aoff + k0 + 16 * E_,   d + 4096 + 512);                       \
        gl_lds16(Bhi + boff + k0,             d + 8192);                             \
        gl_lds16(Bhi + boff + k0 + 16 * E_,   d + 8192 + 512);                       \
        gl_lds16(Blo + boff + k0,             d + 12288);                            \
        gl_lds16(Blo + boff + k0 + 16 * E_,   d + 12288 + 512);                      \
    }

    STAGE_STEP(0, 0);

    for (int ks = 0; ks < 32; ++ks) {
        __syncthreads();                     // drains staging loads (vmcnt) + barrier
        if (ks + 1 < 32) STAGE_STEP(ks + 1, (ks + 1) & 1);
        const unsigned short* sb = smem + (ks & 1) * 16384;
        bf16x8 ah[4], al[4], bh[4], bl[4];
#pragma unroll
        for (int m = 0; m < 4; ++m) {
            int r = wrow + m * 16 + rl;
            int off = r * 32 + ((g ^ (r & 3)) << 3);
            ah[m] = *(const bf16x8*)(sb + off);
            al[m] = *(const bf16x8*)(sb + 4096 + off);
        }
#pragma unroll
        for (int n = 0; n < 4; ++n) {
            int r = wcol + n * 16 + rl;
            int off = r * 32 + ((g ^ (r & 3)) << 3);
            bh[n] = *(const bf16x8*)(sb + 8192 + off);
            bl[n] = *(const bf16x8*)(sb + 12288 + off);
        }
#pragma unroll
        for (int m = 0; m < 4; ++m)
#pragma unroll
            for (int n = 0; n < 4; ++n)
                acc[m][n] = __builtin_amdgcn_mfma_f32_16x16x32_bf16(ah[m], bh[n], acc[m][n], 0, 0, 0);
#pragma unroll
        for (int m = 0; m < 4; ++m)
#pragma unroll
            for (int n = 0; n < 4; ++n)
                acc[m][n] = __builtin_amdgcn_mfma_f32_16x16x32_bf16(ah[m], bl[n], acc[m][n], 0, 0, 0);
#pragma unroll
        for (int m = 0; m < 4; ++m)
#pragma unroll
            for (int n = 0; n < 4; ++n)
                acc[m][n] = __builtin_amdgcn_mfma_f32_16x16x32_bf16(al[m], bh[n], acc[m][n], 0, 0, 0);
    }
#undef STAGE_STEP

    // epilogue: C/D layout col = lane&15, row = (lane>>4)*4 + reg
    float bv[4];
#pragma unroll
    for (int n = 0; n < 4; ++n) bv[n] = bias[col0 + wcol + n * 16 + rl];
#pragma unroll
    for (int m = 0; m < 4; ++m) {
        int rbase = row0 + wrow + m * 16 + g * 4;
#pragma unroll
        for (int n = 0; n < 4; ++n) {
            int c = col0 + wcol + n * 16 + rl;
#pragma unroll
            for (int q = 0; q < 4; ++q) {
                int r = rbase + q;
                float v = acc[m][n][q] + bv[n];
                long off;
                if (OUT_MODE == 0) off = (long)r * E_ + c;
                else { int b = r >> 12, nn = r & (N_ - 1); off = (long)(nn * B_ + b) * E_ + c; }
                Y[off] = v;
            }
        }
    }
}

// ---------------- fp32 fallback GEMM (round-2 proven) ----------------
template<int IN_MODE, int OUT_MODE>
__global__ __launch_bounds__(256) void lin_gemm(const float* __restrict__ X,
                                                const float* __restrict__ W,
                                                const float* __restrict__ bias,
                                                float* __restrict__ Y)
{
    __shared__ float As[16][68];
    __shared__ float Ws[16][68];
    const int row0 = blockIdx.x * 64;
    const int col0 = blockIdx.y * 64;
    const int t  = threadIdx.x;
    const int lr = t >> 2;
    const int lk = (t & 3) * 4;
    const int ty = t >> 4, tx = t & 15;

    long arow;
    {
        int r = row0 + lr;
        if (IN_MODE == 0) { int b = r >> 12, n = r & (N_ - 1); arow = (long)(n * B_ + b) * E_; }
        else              { arow = (long)r * E_; }
    }
    const long wrow = (long)(col0 + lr) * E_;

    float acc[4][4] = {};
    for (int e0 = 0; e0 < E_; e0 += 16) {
        float4 av = *(const float4*)(X + arow + e0 + lk);
        float4 wv = *(const float4*)(W + wrow + e0 + lk);
        As[lk+0][lr] = av.x; As[lk+1][lr] = av.y; As[lk+2][lr] = av.z; As[lk+3][lr] = av.w;
        Ws[lk+0][lr] = wv.x; Ws[lk+1][lr] = wv.y; Ws[lk+2][lr] = wv.z; Ws[lk+3][lr] = wv.w;
        __syncthreads();
#pragma unroll
        for (int k = 0; k < 16; ++k) {
            float4 a = *(const float4*)&As[k][ty*4];
            float4 w = *(const float4*)&Ws[k][tx*4];
            float a_[4] = {a.x,a.y,a.z,a.w};
            float w_[4] = {w.x,w.y,w.z,w.w};
#pragma unroll
            for (int i = 0; i < 4; ++i)
#pragma unroll
                for (int j = 0; j < 4; ++j)
                    acc[i][j] = fmaf(a_[i], w_[j], acc[i][j]);
        }
        __syncthreads();
    }
    float4 bvv = *(const float4*)(bias + col0 + tx*4);
    float b_[4] = {bvv.x,bvv.y,bvv.z,bvv.w};
#pragma unroll
    for (int i = 0; i < 4; ++i) {
        int r = row0 + ty*4 + i;
        float4 o;
        o.x = acc[i][0] + b_[0]; o.y = acc[i][1] + b_[1];
        o.z = acc[i][2] + b_[2]; o.w = acc[i][3] + b_[3];
        long off;
        if (OUT_MODE == 0) off = (long)r * E_ + col0 + tx*4;
        else { int b = r >> 12, n = r & (N_ - 1); off = (long)(n * B_ + b) * E_ + col0 + tx*4; }
        *(float4*)(Y + off) = o;
    }
}

// ---------------- favorp dash (IN-PLACE over [B,N,E]) ----------------
template<int IS_QUERY>
__global__ __launch_bounds__(256) void favorp_dash(float* __restrict__ Xh,
                                                   const float* __restrict__ proj,
                                                   float* __restrict__ stab)
{
    __shared__ float Xs[64][68];
    __shared__ float Ps[64][68];
    __shared__ float diag[64];
    __shared__ float red4[4];
    __shared__ float rowred[64][17];
    const int bh = blockIdx.x, b = bh >> 4, h = bh & 15;
    const int n0 = blockIdx.y * 64;
    const int t = threadIdx.x;
    const int r = t >> 2, c0 = (t & 3) * 16;
    const int ty = t >> 4, tx = t & 15;

    const float* xrow = Xh + (long)(b * N_ + n0 + r) * E_ + h * 64;
    const float* prow = proj + (long)(h * 64 + r) * 64;
#pragma unroll
    for (int c = 0; c < 4; ++c) {
        float4 v = *(const float4*)(xrow + c0 + c*4);
        Xs[c0+c*4+0][r] = v.x; Xs[c0+c*4+1][r] = v.y; Xs[c0+c*4+2][r] = v.z; Xs[c0+c*4+3][r] = v.w;
        float4 p = *(const float4*)(prow + c0 + c*4);
        Ps[c0+c*4+0][r] = p.x; Ps[c0+c*4+1][r] = p.y; Ps[c0+c*4+2][r] = p.z; Ps[c0+c*4+3][r] = p.w;
    }
    __syncthreads();
    if (t < 64) {
        float s = 0.f;
#pragma unroll 16
        for (int d = 0; d < 64; ++d) { float x = Xs[d][t]; s = fmaf(x, x, s); }
        diag[t] = s * DIAG_C;
    }
    __syncthreads();

    float acc[4][4] = {};
#pragma unroll 16
    for (int d = 0; d < 64; ++d) {
        float4 a = *(const float4*)&Xs[d][ty*4];
        float4 p = *(const float4*)&Ps[d][tx*4];
        float a_[4] = {a.x,a.y,a.z,a.w};
        float p_[4] = {p.x,p.y,p.z,p.w};
#pragma unroll
        for (int i = 0; i < 4; ++i)
#pragma unroll
            for (int j = 0; j < 4; ++j)
                acc[i][j] = fmaf(a_[i], p_[j], acc[i][j]);
    }
    float dash[4][4];
#pragma unroll
    for (int i = 0; i < 4; ++i)
#pragma unroll
        for (int j = 0; j < 4; ++j) dash[i][j] = acc[i][j] * NRM_C;

    if (IS_QUERY) {
#pragma unroll
        for (int i = 0; i < 4; ++i) {
            float m = fmaxf(fmaxf(dash[i][0], dash[i][1]), fmaxf(dash[i][2], dash[i][3]));
            rowred[ty*4+i][tx] = m;
        }
        __syncthreads();
#pragma unroll
        for (int i = 0; i < 4; ++i) {
            int row = ty*4 + i;
            float m = rowred[row][0];
#pragma unroll
            for (int jj = 1; jj < 16; ++jj) m = fmaxf(m, rowred[row][jj]);
            float dg = diag[row];
            float4 o;
            o.x = RATIO_C * expf(dash[i][0] - dg - m) + EPSF;
            o.y = RATIO_C * expf(dash[i][1] - dg - m) + EPSF;
            o.z = RATIO_C * expf(dash[i][2] - dg - m) + EPSF;
            o.w = RATIO_C * expf(dash[i][3] - dg - m) + EPSF;
            *(float4*)(Xh + (long)(b * N_ + n0 + row) * E_ + h * 64 + tx*4) = o;
        }
    } else {
        float lmax = dash[0][0];
#pragma unroll
        for (int i = 0; i < 4; ++i)
#pragma unroll
            for (int j = 0; j < 4; ++j) lmax = fmaxf(lmax, dash[i][j]);
#pragma unroll
        for (int i = 0; i < 4; ++i) {
            int row = ty*4 + i;
            float dg = diag[row];
            float4 o = { dash[i][0]-dg, dash[i][1]-dg, dash[i][2]-dg, dash[i][3]-dg };
            *(float4*)(Xh + (long)(b * N_ + n0 + row) * E_ + h * 64 + tx*4) = o;
        }
#pragma unroll
        for (int off = 32; off > 0; off >>= 1) lmax = fmaxf(lmax, __shfl_down(lmax, off));
        if ((t & 63) == 0) red4[t >> 6] = lmax;
        __syncthreads();
        if (t == 0)
            atomicMaxF(&stab[bh], fmaxf(fmaxf(red4[0], red4[1]), fmaxf(red4[2], red4[3])));
    }
}

// ---------------- kv partials ----------------
__global__ __launch_bounds__(256) void kv_partial(const float* __restrict__ T1,
                                                  const float* __restrict__ V,
                                                  const float* __restrict__ stab,
                                                  float* __restrict__ kvp,
                                                  float* __restrict__ ksump)
{
    __shared__ float KPs[16][68];
    __shared__ float Vs[16][68];
    const int bh = blockIdx.x, chunk = blockIdx.y;
    const int b = bh >> 4, h = bh & 15;
    const int t = threadIdx.x;
    const int lr = t >> 4, lm = (t & 15) * 4;
    const int ty = t >> 4, tx = t & 15;
    const float stb = stab[bh];
    float acc[4][4] = {};
    float ks = 0.f;
    const int nbeg = chunk * (N_ / SPLITK), nend = nbeg + (N_ / SPLITK);
    for (int n0 = nbeg; n0 < nend; n0 += 16) {
        long rowoff = (long)(b * N_ + n0 + lr) * E_ + h * 64 + lm;
        float4 tv = *(const float4*)(T1 + rowoff);
        float4 vv = *(const float4*)(V + rowoff);
        KPs[lr][lm+0] = RATIO_C * expf(tv.x - stb) + EPSF;
        KPs[lr][lm+1] = RATIO_C * expf(tv.y - stb) + EPSF;
        KPs[lr][lm+2] = RATIO_C * expf(tv.z - stb) + EPSF;
        KPs[lr][lm+3] = RATIO_C * expf(tv.w - stb) + EPSF;
        *(float4*)&Vs[lr][lm] = vv;
        __syncthreads();
        if (t < 64) {
#pragma unroll
            for (int rr = 0; rr < 16; ++rr) ks += KPs[rr][t];
        }
#pragma unroll
        for (int k = 0; k < 16; ++k) {
            float4 a = *(const float4*)&KPs[k][ty*4];
            float4 v4 = *(const float4*)&Vs[k][tx*4];
            float a_[4] = {a.x,a.y,a.z,a.w};
            float v_[4] = {v4.x,v4.y,v4.z,v4.w};
#pragma unroll
            for (int i = 0; i < 4; ++i)
#pragma unroll
                for (int j = 0; j < 4; ++j)
                    acc[i][j] = fmaf(a_[i], v_[j], acc[i][j]);
        }
        __syncthreads();
    }
    const long kvbase = ((long)chunk * BH_ + bh) * 4096;
#pragma unroll
    for (int i = 0; i < 4; ++i) {
        float4 o = {acc[i][0], acc[i][1], acc[i][2], acc[i][3]};
        *(float4*)(kvp + kvbase + (ty*4+i) * 64 + tx*4) = o;
    }
    if (t < 64) ksump[((long)chunk * BH_ + bh) * 64 + t] = ks;
}

__global__ __launch_bounds__(256) void kv_reduce(const float* __restrict__ kvp,
                                                 const float* __restrict__ ksump,
                                                 float* __restrict__ kv,
                                                 float* __restrict__ ksum)
{
    int idx = blockIdx.x * 256 + threadIdx.x;
    if (idx < BH_ * 4096) {
        float s = 0.f;
#pragma unroll
        for (int c = 0; c < SPLITK; ++c) s += kvp[(long)c * BH_ * 4096 + idx];
        kv[idx] = s;
    } else {
        int j = idx - BH_ * 4096;
        if (j < BH_ * 64) {
            float s = 0.f;
#pragma unroll
            for (int c = 0; c < SPLITK; ++c) s += ksump[(long)c * BH_ * 64 + j];
            ksum[j] = s;
        }
    }
}

// ---------------- qkv + normalize ----------------
// SPLIT=0: write fp32 attn [B,N,E].  SPLIT=1: write bf16 hi/lo [BN,E] (GEMM-ready).
template<int SPLIT>
__global__ __launch_bounds__(256) void qkv_attn(const float* __restrict__ Qp,
                                                const float* __restrict__ kvM,
                                                const float* __restrict__ ksum,
                                                float* __restrict__ attn,
                                                unsigned short* __restrict__ Ohi,
                                                unsigned short* __restrict__ Olo)
{
    __shared__ float QPs[64][68];
    __shared__ float kvs[64][68];
    __shared__ float ksums[64];
    __shared__ float rnorm[64];
    const int bh = blockIdx.x, b = bh >> 4, h = bh & 15;
    const int n0 = blockIdx.y * 64;
    const int t = threadIdx.x;
    const int r = t >> 2, c0 = (t & 3) * 16;
    const int ty = t >> 4, tx = t & 15;

#pragma unroll
    for (int c = 0; c < 4; ++c) {
        int idx = t * 16 + c * 4;
        float4 v = *(const float4*)(kvM + (long)bh * 4096 + idx);
        *(float4*)&kvs[idx >> 6][idx & 63] = v;
    }
    if (t < 64) ksums[t] = ksum[bh * 64 + t];
    const float* qrow = Qp + (long)(b * N_ + n0 + r) * E_ + h * 64;
#pragma unroll
    for (int c = 0; c < 4; ++c) {
        float4 v = *(const float4*)(qrow + c0 + c*4);
        QPs[c0+c*4+0][r] = v.x; QPs[c0+c*4+1][r] = v.y; QPs[c0+c*4+2][r] = v.z; QPs[c0+c*4+3][r] = v.w;
    }
    __syncthreads();
    if (t < 64) {
        float s = 0.f;
#pragma unroll 16
        for (int m = 0; m < 64; ++m) s = fmaf(QPs[m][t], ksums[m], s);
        rnorm[t] = 1.f / fmaxf(s, EPSD);
    }
    __syncthreads();
    float acc[4][4] = {};
#pragma unroll 16
    for (int m = 0; m < 64; ++m) {
        float4 a = *(const float4*)&QPs[m][ty*4];
        float4 v4 = *(const float4*)&kvs[m][tx*4];
        float a_[4] = {a.x,a.y,a.z,a.w};
        float v_[4] = {v4.x,v4.y,v4.z,v4.w};
#pragma unroll
        for (int i = 0; i < 4; ++i)
#pragma unroll
            for (int j = 0; j < 4; ++j)
                acc[i][j] = fmaf(a_[i], v_[j], acc[i][j]);
    }
#pragma unroll
    for (int i = 0; i < 4; ++i) {
        int row = ty*4 + i;
        float rn = rnorm[row];
        float4 o = {acc[i][0]*rn, acc[i][1]*rn, acc[i][2]*rn, acc[i][3]*rn};
        if (SPLIT) {
            long off = (((long)(b * N_ + n0 + row)) << 10) + h * 64 + tx * 4;
            ushort4 hh, ll;
            hh.x = f32_to_bf16(o.x); ll.x = f32_to_bf16(o.x - bf16_to_f32(hh.x));
            hh.y = f32_to_bf16(o.y); ll.y = f32_to_bf16(o.y - bf16_to_f32(hh.y));
            hh.z = f32_to_bf16(o.z); ll.z = f32_to_bf16(o.z - bf16_to_f32(hh.z));
            hh.w = f32_to_bf16(o.w); ll.w = f32_to_bf16(o.w - bf16_to_f32(hh.w));
            *(ushort4*)(Ohi + off) = hh;
            *(ushort4*)(Olo + off) = ll;
        } else {
            *(float4*)(attn + (long)(b * N_ + n0 + row) * E_ + h * 64 + tx*4) = o;
        }
    }
}

extern "C" void kernel_launch(void* const* d_in, const int* in_sizes, int n_in,
                              void* d_out, int out_size, void* d_ws, size_t ws_size,
                              hipStream_t stream)
{
    const float* query = (const float*)d_in[0];
    const float* key   = (const float*)d_in[1];
    const float* value = (const float*)d_in[2];
    const float* Wq    = (const float*)d_in[3];
    const float* bq    = (const float*)d_in[4];
    const float* Wk    = (const float*)d_in[5];
    const float* bk    = (const float*)d_in[6];
    const float* Wv    = (const float*)d_in[7];
    const float* bv    = (const float*)d_in[8];
    const float* Wo    = (const float*)d_in[9];
    const float* bo    = (const float*)d_in[10];
    const float* proj  = (const float*)d_in[11];
    float* O = (float*)d_out;                 // scratch; fully rewritten by final GEMM

    float* ws = (float*)d_ws;
    const size_t SZ = (size_t)BN_ * E_;       // 16.78M
    float* A     = ws;                        // V fp32 (fallback: also attn)
    float* kvp   = ws + SZ;
    float* ksump = kvp + (size_t)SPLITK * BH_ * 4096;
    float* kvM   = ksump + (size_t)SPLITK * BH_ * 64;
    float* ksum  = kvM + (size_t)BH_ * 4096;
    float* stab  = ksum + (size_t)BH_ * 64;
    const size_t COMMON = SZ + (size_t)SPLITK * BH_ * 4096 + (size_t)SPLITK * BH_ * 64
                        + (size_t)BH_ * 4096 + (size_t)BH_ * 64 + 64;
    unsigned short* Xhi = (unsigned short*)(ws + COMMON);
    unsigned short* Xlo = Xhi + SZ;
    unsigned short* Whi = Xlo + SZ;
    unsigned short* Wlo = Whi + (size_t)E_ * E_;
    const size_t NEED_FAST = (COMMON + SZ + (size_t)E_ * E_) * 4;  // bytes

    dim3 gF(BH_, N_ / 64);
    dim3 gKV(BH_, SPLITK);
    const int nRed = (BH_ * 4096 + BH_ * 64) / 256;

    if (ws_size >= NEED_FAST) {
        dim3 gG(BN_ / 128, E_ / 128);
        const int X4 = (int)(SZ / 4), W4 = (E_ * E_) / 4;
        // K
        convert_split<0><<<2048, 256, 0, stream>>>(key, Xhi, Xlo, X4);
        convert_split<1><<<1024, 256, 0, stream>>>(Wk, Whi, Wlo, W4);
        gemm_mfma<0><<<gG, 256, 0, stream>>>(Xhi, Xlo, Whi, Wlo, bk, O);
        init_stab<<<1, 64, 0, stream>>>(stab);
        favorp_dash<0><<<gF, 256, 0, stream>>>(O, proj, stab);
        // V
        convert_split<0><<<2048, 256, 0, stream>>>(value, Xhi, Xlo, X4);
        convert_split<1><<<1024, 256, 0, stream>>>(Wv, Whi, Wlo, W4);
        gemm_mfma<0><<<gG, 256, 0, stream>>>(Xhi, Xlo, Whi, Wlo, bv, A);
        kv_partial<<<gKV, 256, 0, stream>>>(O, A, stab, kvp, ksump);
        kv_reduce<<<nRed, 256, 0, stream>>>(kvp, ksump, kvM, ksum);
        // Q
        convert_split<0><<<2048, 256, 0, stream>>>(query, Xhi, Xlo, X4);
        convert_split<1><<<1024, 256, 0, stream>>>(Wq, Whi, Wlo, W4);
        gemm_mfma<0><<<gG, 256, 0, stream>>>(Xhi, Xlo, Whi, Wlo, bq, O);
        favorp_dash<1><<<gF, 256, 0, stream>>>(O, proj, stab);
        // attn (writes split bf16 directly)
        qkv_attn<1><<<gF, 256, 0, stream>>>(O, kvM, ksum, nullptr, Xhi, Xlo);
        // out
        convert_split<1><<<1024, 256, 0, stream>>>(Wo, Whi, Wlo, W4);
        gemm_mfma<1><<<gG, 256, 0, stream>>>(Xhi, Xlo, Whi, Wlo, bo, O);
    } else {
        // fp32 fallback (round-2 proven path)
        dim3 gGemm(BN_ / 64, E_ / 64);
        lin_gemm<0,0><<<gGemm, 256, 0, stream>>>(key, Wk, bk, O);
        init_stab<<<1, 64, 0, stream>>>(stab);
        favorp_dash<0><<<gF, 256, 0, stream>>>(O, proj, stab);
        lin_gemm<0,0><<<gGemm, 256, 0, stream>>>(value, Wv, bv, A);
        kv_partial<<<gKV, 256, 0, stream>>>(O, A, stab, kvp, ksump);
        kv_reduce<<<nRed, 256, 0, stream>>>(kvp, ksump, kvM, ksum);
        lin_gemm<0,0><<<gGemm, 256, 0, stream>>>(query, Wq, bq, O);
        favorp_dash<1><<<gF, 256, 0, stream>>>(O, proj, stab);
        qkv_attn<0><<<gF, 256, 0, stream>>>(O, kvM, ksum, A, nullptr, nullptr);
        lin_gemm<1,1><<<gGemm, 256, 0, stream>>>(A, Wo, bo, O);
    }
}

// Round 4
// 625.329 us; speedup vs baseline: 3.2038x; 1.0666x over previous
//
#include <hip/hip_runtime.h>
#include <math.h>

// Problem constants (fixed by setup_inputs)
#define B_   4
#define N_   4096
#define E_   1024
#define H_   16
#define BN_  (B_*N_)
#define BH_  (B_*H_)
#define SPLITK 8

// favorp constants
#define NRM_C   0.35355339059327373f   // 64^-0.25
#define DIAG_C  0.0625f                // 0.5 * NRM^2
#define RATIO_C 0.125f                 // 64^-0.5
#define EPSF    1e-4f
#define EPSD    0.01f

typedef __attribute__((ext_vector_type(8))) short bf16x8;   // 8 bf16 in 4 VGPRs
typedef __attribute__((ext_vector_type(4))) float f32x4;

__device__ __forceinline__ unsigned short f32_to_bf16(float x) {
    unsigned int u = __float_as_uint(x);
    unsigned int r = (u + 0x7fffu + ((u >> 16) & 1u)) >> 16;   // RTN-even
    return (unsigned short)r;
}
__device__ __forceinline__ float bf16_to_f32(unsigned short h) {
    return __uint_as_float(((unsigned int)h) << 16);
}

__device__ __forceinline__ void atomicMaxF(float* addr, float v) {
    if (v >= 0.f) atomicMax((int*)addr, __float_as_int(v));
    else          atomicMin((unsigned int*)addr, __float_as_uint(v));
}

__global__ void init_stab(float* stab) {
    if (threadIdx.x < BH_) stab[threadIdx.x] = -INFINITY;
}

// ---------------- split-bf16 conversion ----------------
// IN_MODE 0: src is [N,B,E] (gather to row r=b*N+n). IN_MODE 1: row-major copy.
template<int IN_MODE>
__global__ __launch_bounds__(256) void convert_split(const float* __restrict__ src,
                                                     unsigned short* __restrict__ hi,
                                                     unsigned short* __restrict__ lo,
                                                     int total4)
{
    int i = blockIdx.x * 256 + threadIdx.x;
    const int stride = gridDim.x * 256;
    for (; i < total4; i += stride) {
        long e4 = (long)i * 4;
        const float* p;
        if (IN_MODE == 0) {
            long r = e4 >> 10; int e = (int)(e4 & 1023);
            int b = (int)(r >> 12), n = (int)(r & 4095);
            p = src + (((long)(n * B_ + b)) << 10) + e;
        } else {
            p = src + e4;
        }
        float4 v = *(const float4*)p;
        ushort4 h, l;
        h.x = f32_to_bf16(v.x); l.x = f32_to_bf16(v.x - bf16_to_f32(h.x));
        h.y = f32_to_bf16(v.y); l.y = f32_to_bf16(v.y - bf16_to_f32(h.y));
        h.z = f32_to_bf16(v.z); l.z = f32_to_bf16(v.z - bf16_to_f32(h.z));
        h.w = f32_to_bf16(v.w); l.w = f32_to_bf16(v.w - bf16_to_f32(h.w));
        *(ushort4*)(hi + e4) = h;
        *(ushort4*)(lo + e4) = l;
    }
}

// ---------------- MFMA split-bf16 GEMM: Y = X @ W^T + bias ----------------
// MODE 0: Y fp32 [BN,E]                 (V GEMM)
// MODE 1: Y fp32 [N,B,E] transposed     (output GEMM)
// MODE 2: K-fused: write T1 = dash - diag (fp32, [BN,E]) + atomicMax stab
// MODE 3: Q-fused: favorp_q + qkv + normalize, write attn split-bf16 [BN,E]
__device__ __forceinline__ void gl_lds16(const unsigned short* g, unsigned short* l) {
    __builtin_amdgcn_global_load_lds((const __attribute__((address_space(1))) void*)g,
                                     (__attribute__((address_space(3))) void*)l, 16, 0, 0);
}

#define SMEM_BYTES (4*64*68*4 + 2*4*64*4)   // accF[4][64][68] f32 + diag[4][64] + rnorm[4][64]

template<int MODE>
__global__ __launch_bounds__(256) void gemm_mfma(const unsigned short* __restrict__ Ahi,
                                                 const unsigned short* __restrict__ Alo,
                                                 const unsigned short* __restrict__ Bhi,
                                                 const unsigned short* __restrict__ Blo,
                                                 const float* __restrict__ bias,
                                                 float* __restrict__ Y,          // MODE 0/1/2 fp32 out
                                                 float* __restrict__ stab,       // MODE 2
                                                 const unsigned short* __restrict__ PShi, // MODE 2/3
                                                 const unsigned short* __restrict__ PSlo,
                                                 const unsigned short* __restrict__ kvThi, // MODE 3
                                                 const unsigned short* __restrict__ kvTlo,
                                                 const float* __restrict__ ksum,           // MODE 3
                                                 unsigned short* __restrict__ AttnHi,      // MODE 3
                                                 unsigned short* __restrict__ AttnLo)
{
    __shared__ __align__(16) char SMEM[SMEM_BYTES];
    unsigned short* smem = (unsigned short*)SMEM;            // staging union (64KB)
    const int t = threadIdx.x;
    const int w = t >> 6, lane = t & 63;
    const int row0 = blockIdx.x * 128, col0 = blockIdx.y * 128;
    const int wrow = (w >> 1) * 64, wcol = (w & 1) * 64;
    const int g = lane >> 4, rl = lane & 15;

    const int sr = w * 32 + (lane >> 2);
    const int kswz = (((lane & 3) ^ ((lane >> 2) & 3)) << 3);
    const long aoff = (long)(row0 + sr) * E_ + kswz;
    const long boff = (long)(col0 + sr) * E_ + kswz;

    f32x4 acc[4][4];
#pragma unroll
    for (int m = 0; m < 4; ++m)
#pragma unroll
        for (int n = 0; n < 4; ++n) acc[m][n] = (f32x4){0.f, 0.f, 0.f, 0.f};

#define STAGE_STEP(KS, BUF)                                                          \
    {                                                                                \
        const int k0 = (KS) * 32;                                                    \
        unsigned short* d = smem + (BUF) * 16384 + w * 1024;                         \
        gl_lds16(Ahi + aoff + k0,             d);                                    \
        gl_lds16(Ahi + aoff + k0 + 16 * E_,   d + 512);                              \
        gl_lds16(Alo + aoff + k0,             d + 4096);                             \
        gl_lds16(Alo + aoff + k0 + 16 * E_,   d + 4096 + 512);                       \
        gl_lds16(Bhi + boff + k0,             d + 8192);                             \
        gl_lds16(Bhi + boff + k0 + 16 * E_,   d + 8192 + 512);                       \
        gl_lds16(Blo + boff + k0,             d + 12288);                            \
        gl_lds16(Blo + boff + k0 + 16 * E_,   d + 12288 + 512);                      \
    }

    STAGE_STEP(0, 0);

    for (int ks = 0; ks < 32; ++ks) {
        __syncthreads();
        if (ks + 1 < 32) STAGE_STEP(ks + 1, (ks + 1) & 1);
        const unsigned short* sb = smem + (ks & 1) * 16384;
        bf16x8 ah[4], al[4], bh[4], bl[4];
#pragma unroll
        for (int m = 0; m < 4; ++m) {
            int r = wrow + m * 16 + rl;
            int off = r * 32 + ((g ^ (r & 3)) << 3);
            ah[m] = *(const bf16x8*)(sb + off);
            al[m] = *(const bf16x8*)(sb + 4096 + off);
        }
#pragma unroll
        for (int n = 0; n < 4; ++n) {
            int r = wcol + n * 16 + rl;
            int off = r * 32 + ((g ^ (r & 3)) << 3);
            bh[n] = *(const bf16x8*)(sb + 8192 + off);
            bl[n] = *(const bf16x8*)(sb + 12288 + off);
        }
#pragma unroll
        for (int m = 0; m < 4; ++m)
#pragma unroll
            for (int n = 0; n < 4; ++n)
                acc[m][n] = __builtin_amdgcn_mfma_f32_16x16x32_bf16(ah[m], bh[n], acc[m][n], 0, 0, 0);
#pragma unroll
        for (int m = 0; m < 4; ++m)
#pragma unroll
            for (int n = 0; n < 4; ++n)
                acc[m][n] = __builtin_amdgcn_mfma_f32_16x16x32_bf16(ah[m], bl[n], acc[m][n], 0, 0, 0);
#pragma unroll
        for (int m = 0; m < 4; ++m)
#pragma unroll
            for (int n = 0; n < 4; ++n)
                acc[m][n] = __builtin_amdgcn_mfma_f32_16x16x32_bf16(al[m], bh[n], acc[m][n], 0, 0, 0);
    }
#undef STAGE_STEP

    float bv[4];
#pragma unroll
    for (int n = 0; n < 4; ++n) bv[n] = bias[col0 + wcol + n * 16 + rl];

    if (MODE <= 1) {
        // plain epilogue: C/D layout col = lane&15, row = (lane>>4)*4 + reg
#pragma unroll
        for (int m = 0; m < 4; ++m) {
            int rbase = row0 + wrow + m * 16 + g * 4;
#pragma unroll
            for (int n = 0; n < 4; ++n) {
                int c = col0 + wcol + n * 16 + rl;
#pragma unroll
                for (int q = 0; q < 4; ++q) {
                    int r = rbase + q;
                    float v = acc[m][n][q] + bv[n];
                    long off;
                    if (MODE == 0) off = (long)r * E_ + c;
                    else { int b = r >> 12, nn = r & (N_ - 1); off = (long)(nn * B_ + b) * E_ + c; }
                    Y[off] = v;
                }
            }
        }
        return;
    }

    // ---------------- fused favorp epilogue (MODE 2 / 3) ----------------
    __syncthreads();   // all staging reads of last tile done; smem reusable
    float* accF  = (float*)SMEM + w * (64 * 68);              // wave-private [64][68]
    float* diagL = (float*)(SMEM + 4*64*68*4) + w * 64;
    float* rnmL  = (float*)(SMEM + 4*64*68*4) + 256 + w * 64;
    const int b_idx = row0 >> 12;
    const int hg = (col0 >> 6) + (w & 1);                     // global head 0..15
    const int bh = b_idx * H_ + hg;

    // acc (+bias) -> accF (wave quadrant: rows wrow..+64 of head hg)
#pragma unroll
    for (int m = 0; m < 4; ++m)
#pragma unroll
        for (int n = 0; n < 4; ++n)
#pragma unroll
            for (int q = 0; q < 4; ++q)
                accF[(m*16 + g*4 + q) * 68 + n*16 + rl] = acc[m][n][q] + bv[n];
    // diag per row (lane -> row lane)
    {
        float s = 0.f;
#pragma unroll 16
        for (int d = 0; d < 64; ++d) { float x = accF[lane * 68 + d]; s = fmaf(x, x, s); }
        diagL[lane] = s * DIAG_C;
    }
    __syncthreads();

    float wavemax = -INFINITY;
#pragma unroll
    for (int mi = 0; mi < 4; ++mi) {
        // A-frags from accF rows mi*16+rl, split to bf16 hi/lo
        bf16x8 dah[2], dal[2];
#pragma unroll
        for (int kk = 0; kk < 2; ++kk) {
            const float* src = &accF[(mi*16 + rl) * 68 + kk*32 + g*8];
            float4 f0 = *(const float4*)src, f1 = *(const float4*)(src + 4);
            float fv[8] = {f0.x,f0.y,f0.z,f0.w,f1.x,f1.y,f1.z,f1.w};
            bf16x8 hh, ll;
#pragma unroll
            for (int j = 0; j < 8; ++j) {
                unsigned short h16 = f32_to_bf16(fv[j]);
                hh[j] = (short)h16;
                ll[j] = (short)f32_to_bf16(fv[j] - bf16_to_f32(h16));
            }
            dah[kk] = hh; dal[kk] = ll;
        }
        // dash = NRM * (K/Q · proj^T), 3-product split-bf16
        f32x4 dacc[4];
#pragma unroll
        for (int n = 0; n < 4; ++n) dacc[n] = (f32x4){0.f,0.f,0.f,0.f};
#pragma unroll
        for (int n = 0; n < 4; ++n)
#pragma unroll
            for (int kk = 0; kk < 2; ++kk) {
                long po = (long)hg * 4096 + (n*16 + rl) * 64 + kk*32 + g*8;
                bf16x8 pbh = *(const bf16x8*)(PShi + po);
                bf16x8 pbl = *(const bf16x8*)(PSlo + po);
                dacc[n] = __builtin_amdgcn_mfma_f32_16x16x32_bf16(dah[kk], pbh, dacc[n], 0, 0, 0);
                dacc[n] = __builtin_amdgcn_mfma_f32_16x16x32_bf16(dah[kk], pbl, dacc[n], 0, 0, 0);
                dacc[n] = __builtin_amdgcn_mfma_f32_16x16x32_bf16(dal[kk], pbh, dacc[n], 0, 0, 0);
            }
        if (MODE == 2) {
#pragma unroll
            for (int n = 0; n < 4; ++n)
#pragma unroll
                for (int q = 0; q < 4; ++q) {
                    float dsh = dacc[n][q] * NRM_C;
                    wavemax = fmaxf(wavemax, dsh);
                    int rloc = mi*16 + g*4 + q;
                    Y[(long)(row0 + wrow + rloc) * E_ + col0 + wcol + n*16 + rl] = dsh - diagL[rloc];
                }
        } else {
            // rowmax over the 64 proj features
            float rm0 = -INFINITY, rm1 = -INFINITY, rm2 = -INFINITY, rm3 = -INFINITY;
#pragma unroll
            for (int n = 0; n < 4; ++n) {
                rm0 = fmaxf(rm0, dacc[n][0]); rm1 = fmaxf(rm1, dacc[n][1]);
                rm2 = fmaxf(rm2, dacc[n][2]); rm3 = fmaxf(rm3, dacc[n][3]);
            }
#pragma unroll
            for (int off = 1; off < 16; off <<= 1) {
                rm0 = fmaxf(rm0, __shfl_xor(rm0, off));
                rm1 = fmaxf(rm1, __shfl_xor(rm1, off));
                rm2 = fmaxf(rm2, __shfl_xor(rm2, off));
                rm3 = fmaxf(rm3, __shfl_xor(rm3, off));
            }
            float rmq[4] = {rm0 * NRM_C, rm1 * NRM_C, rm2 * NRM_C, rm3 * NRM_C};
#pragma unroll
            for (int n = 0; n < 4; ++n)
#pragma unroll
                for (int q = 0; q < 4; ++q) {
                    int rloc = mi*16 + g*4 + q;
                    float qp = RATIO_C * expf(dacc[n][q] * NRM_C - diagL[rloc] - rmq[q]) + EPSF;
                    accF[rloc * 68 + n*16 + rl] = qp;   // overwrite (this 16-row band is done)
                }
        }
    }

    if (MODE == 2) {
#pragma unroll
        for (int off = 1; off < 64; off <<= 1) wavemax = fmaxf(wavemax, __shfl_xor(wavemax, off));
        if (lane == 0) atomicMaxF(&stab[bh], wavemax);
        return;
    }

    // MODE 3: normalizer, then qkv via MFMA against kvT
    {
        float s = 0.f;
        const float* kb = ksum + bh * 64;
#pragma unroll 16
        for (int m = 0; m < 64; ++m) s = fmaf(accF[lane * 68 + m], kb[m], s);
        rnmL[lane] = 1.f / fmaxf(s, EPSD);
    }
    __syncthreads();
#pragma unroll
    for (int mi = 0; mi < 4; ++mi) {
        bf16x8 qah[2], qal[2];
#pragma unroll
        for (int kk = 0; kk < 2; ++kk) {
            const float* src = &accF[(mi*16 + rl) * 68 + kk*32 + g*8];
            float4 f0 = *(const float4*)src, f1 = *(const float4*)(src + 4);
            float fv[8] = {f0.x,f0.y,f0.z,f0.w,f1.x,f1.y,f1.z,f1.w};
            bf16x8 hh, ll;
#pragma unroll
            for (int j = 0; j < 8; ++j) {
                unsigned short h16 = f32_to_bf16(fv[j]);
                hh[j] = (short)h16;
                ll[j] = (short)f32_to_bf16(fv[j] - bf16_to_f32(h16));
            }
            qah[kk] = hh; qal[kk] = ll;
        }
        f32x4 oacc[4];
#pragma unroll
        for (int n = 0; n < 4; ++n) oacc[n] = (f32x4){0.f,0.f,0.f,0.f};
#pragma unroll
        for (int n = 0; n < 4; ++n)
#pragma unroll
            for (int kk = 0; kk < 2; ++kk) {
                long ko = (long)bh * 4096 + (n*16 + rl) * 64 + kk*32 + g*8;
                bf16x8 kbh = *(const bf16x8*)(kvThi + ko);
                bf16x8 kbl = *(const bf16x8*)(kvTlo + ko);
                oacc[n] = __builtin_amdgcn_mfma_f32_16x16x32_bf16(qah[kk], kbh, oacc[n], 0, 0, 0);
                oacc[n] = __builtin_amdgcn_mfma_f32_16x16x32_bf16(qah[kk], kbl, oacc[n], 0, 0, 0);
                oacc[n] = __builtin_amdgcn_mfma_f32_16x16x32_bf16(qal[kk], kbh, oacc[n], 0, 0, 0);
            }
#pragma unroll
        for (int n = 0; n < 4; ++n)
#pragma unroll
            for (int q = 0; q < 4; ++q) {
                int rloc = mi*16 + g*4 + q;
                float o = oacc[n][q] * rnmL[rloc];
                long off = (long)(row0 + wrow + rloc) * E_ + col0 + wcol + n*16 + rl;
                unsigned short h16 = f32_to_bf16(o);
                AttnHi[off] = h16;
                AttnLo[off] = f32_to_bf16(o - bf16_to_f32(h16));
            }
    }
}

// ---------------- fp32 fallback GEMM (round-2 proven) ----------------
template<int IN_MODE, int OUT_MODE>
__global__ __launch_bounds__(256) void lin_gemm(const float* __restrict__ X,
                                                const float* __restrict__ W,
                                                const float* __restrict__ bias,
                                                float* __restrict__ Y)
{
    __shared__ float As[16][68];
    __shared__ float Ws[16][68];
    const int row0 = blockIdx.x * 64;
    const int col0 = blockIdx.y * 64;
    const int t  = threadIdx.x;
    const int lr = t >> 2;
    const int lk = (t & 3) * 4;
    const int ty = t >> 4, tx = t & 15;

    long arow;
    {
        int r = row0 + lr;
        if (IN_MODE == 0) { int b = r >> 12, n = r & (N_ - 1); arow = (long)(n * B_ + b) * E_; }
        else              { arow = (long)r * E_; }
    }
    const long wrow = (long)(col0 + lr) * E_;

    float acc[4][4] = {};
    for (int e0 = 0; e0 < E_; e0 += 16) {
        float4 av = *(const float4*)(X + arow + e0 + lk);
        float4 wv = *(const float4*)(W + wrow + e0 + lk);
        As[lk+0][lr] = av.x; As[lk+1][lr] = av.y; As[lk+2][lr] = av.z; As[lk+3][lr] = av.w;
        Ws[lk+0][lr] = wv.x; Ws[lk+1][lr] = wv.y; Ws[lk+2][lr] = wv.z; Ws[lk+3][lr] = wv.w;
        __syncthreads();
#pragma unroll
        for (int k = 0; k < 16; ++k) {
            float4 a = *(const float4*)&As[k][ty*4];
            float4 w = *(const float4*)&Ws[k][tx*4];
            float a_[4] = {a.x,a.y,a.z,a.w};
            float w_[4] = {w.x,w.y,w.z,w.w};
#pragma unroll
            for (int i = 0; i < 4; ++i)
#pragma unroll
                for (int j = 0; j < 4; ++j)
                    acc[i][j] = fmaf(a_[i], w_[j], acc[i][j]);
        }
        __syncthreads();
    }
    float4 bvv = *(const float4*)(bias + col0 + tx*4);
    float b_[4] = {bvv.x,bvv.y,bvv.z,bvv.w};
#pragma unroll
    for (int i = 0; i < 4; ++i) {
        int r = row0 + ty*4 + i;
        float4 o;
        o.x = acc[i][0] + b_[0]; o.y = acc[i][1] + b_[1];
        o.z = acc[i][2] + b_[2]; o.w = acc[i][3] + b_[3];
        long off;
        if (OUT_MODE == 0) off = (long)r * E_ + col0 + tx*4;
        else { int b = r >> 12, n = r & (N_ - 1); off = (long)(n * B_ + b) * E_ + col0 + tx*4; }
        *(float4*)(Y + off) = o;
    }
}

// ---------------- favorp dash (fallback, IN-PLACE over [B,N,E]) ----------------
template<int IS_QUERY>
__global__ __launch_bounds__(256) void favorp_dash(float* __restrict__ Xh,
                                                   const float* __restrict__ proj,
                                                   float* __restrict__ stab)
{
    __shared__ float Xs[64][68];
    __shared__ float Ps[64][68];
    __shared__ float diag[64];
    __shared__ float red4[4];
    __shared__ float rowred[64][17];
    const int bh = blockIdx.x, b = bh >> 4, h = bh & 15;
    const int n0 = blockIdx.y * 64;
    const int t = threadIdx.x;
    const int r = t >> 2, c0 = (t & 3) * 16;
    const int ty = t >> 4, tx = t & 15;

    const float* xrow = Xh + (long)(b * N_ + n0 + r) * E_ + h * 64;
    const float* prow = proj + (long)(h * 64 + r) * 64;
#pragma unroll
    for (int c = 0; c < 4; ++c) {
        float4 v = *(const float4*)(xrow + c0 + c*4);
        Xs[c0+c*4+0][r] = v.x; Xs[c0+c*4+1][r] = v.y; Xs[c0+c*4+2][r] = v.z; Xs[c0+c*4+3][r] = v.w;
        float4 p = *(const float4*)(prow + c0 + c*4);
        Ps[c0+c*4+0][r] = p.x; Ps[c0+c*4+1][r] = p.y; Ps[c0+c*4+2][r] = p.z; Ps[c0+c*4+3][r] = p.w;
    }
    __syncthreads();
    if (t < 64) {
        float s = 0.f;
#pragma unroll 16
        for (int d = 0; d < 64; ++d) { float x = Xs[d][t]; s = fmaf(x, x, s); }
        diag[t] = s * DIAG_C;
    }
    __syncthreads();

    float acc[4][4] = {};
#pragma unroll 16
    for (int d = 0; d < 64; ++d) {
        float4 a = *(const float4*)&Xs[d][ty*4];
        float4 p = *(const float4*)&Ps[d][tx*4];
        float a_[4] = {a.x,a.y,a.z,a.w};
        float p_[4] = {p.x,p.y,p.z,p.w};
#pragma unroll
        for (int i = 0; i < 4; ++i)
#pragma unroll
            for (int j = 0; j < 4; ++j)
                acc[i][j] = fmaf(a_[i], p_[j], acc[i][j]);
    }
    float dash[4][4];
#pragma unroll
    for (int i = 0; i < 4; ++i)
#pragma unroll
        for (int j = 0; j < 4; ++j) dash[i][j] = acc[i][j] * NRM_C;

    if (IS_QUERY) {
#pragma unroll
        for (int i = 0; i < 4; ++i) {
            float m = fmaxf(fmaxf(dash[i][0], dash[i][1]), fmaxf(dash[i][2], dash[i][3]));
            rowred[ty*4+i][tx] = m;
        }
        __syncthreads();
#pragma unroll
        for (int i = 0; i < 4; ++i) {
            int row = ty*4 + i;
            float m = rowred[row][0];
#pragma unroll
            for (int jj = 1; jj < 16; ++jj) m = fmaxf(m, rowred[row][jj]);
            float dg = diag[row];
            float4 o;
            o.x = RATIO_C * expf(dash[i][0] - dg - m) + EPSF;
            o.y = RATIO_C * expf(dash[i][1] - dg - m) + EPSF;
            o.z = RATIO_C * expf(dash[i][2] - dg - m) + EPSF;
            o.w = RATIO_C * expf(dash[i][3] - dg - m) + EPSF;
            *(float4*)(Xh + (long)(b * N_ + n0 + row) * E_ + h * 64 + tx*4) = o;
        }
    } else {
        float lmax = dash[0][0];
#pragma unroll
        for (int i = 0; i < 4; ++i)
#pragma unroll
            for (int j = 0; j < 4; ++j) lmax = fmaxf(lmax, dash[i][j]);
#pragma unroll
        for (int i = 0; i < 4; ++i) {
            int row = ty*4 + i;
            float dg = diag[row];
            float4 o = { dash[i][0]-dg, dash[i][1]-dg, dash[i][2]-dg, dash[i][3]-dg };
            *(float4*)(Xh + (long)(b * N_ + n0 + row) * E_ + h * 64 + tx*4) = o;
        }
#pragma unroll
        for (int off = 32; off > 0; off >>= 1) lmax = fmaxf(lmax, __shfl_down(lmax, off));
        if ((t & 63) == 0) red4[t >> 6] = lmax;
        __syncthreads();
        if (t == 0)
            atomicMaxF(&stab[bh], fmaxf(fmaxf(red4[0], red4[1]), fmaxf(red4[2], red4[3])));
    }
}

// ---------------- kv partials ----------------
__global__ __launch_bounds__(256) void kv_partial(const float* __restrict__ T1,
                                                  const float* __restrict__ V,
                                                  const float* __restrict__ stab,
                                                  float* __restrict__ kvp,
                                                  float* __restrict__ ksump)
{
    __shared__ float KPs[16][68];
    __shared__ float Vs[16][68];
    const int bh = blockIdx.x, chunk = blockIdx.y;
    const int b = bh >> 4, h = bh & 15;
    const int t = threadIdx.x;
    const int lr = t >> 4, lm = (t & 15) * 4;
    const int ty = t >> 4, tx = t & 15;
    const float stb = stab[bh];
    float acc[4][4] = {};
    float ks = 0.f;
    const int nbeg = chunk * (N_ / SPLITK), nend = nbeg + (N_ / SPLITK);
    for (int n0 = nbeg; n0 < nend; n0 += 16) {
        long rowoff = (long)(b * N_ + n0 + lr) * E_ + h * 64 + lm;
        float4 tv = *(const float4*)(T1 + rowoff);
        float4 vv = *(const float4*)(V + rowoff);
        KPs[lr][lm+0] = RATIO_C * expf(tv.x - stb) + EPSF;
        KPs[lr][lm+1] = RATIO_C * expf(tv.y - stb) + EPSF;
        KPs[lr][lm+2] = RATIO_C * expf(tv.z - stb) + EPSF;
        KPs[lr][lm+3] = RATIO_C * expf(tv.w - stb) + EPSF;
        *(float4*)&Vs[lr][lm] = vv;
        __syncthreads();
        if (t < 64) {
#pragma unroll
            for (int rr = 0; rr < 16; ++rr) ks += KPs[rr][t];
        }
#pragma unroll
        for (int k = 0; k < 16; ++k) {
            float4 a = *(const float4*)&KPs[k][ty*4];
            float4 v4 = *(const float4*)&Vs[k][tx*4];
            float a_[4] = {a.x,a.y,a.z,a.w};
            float v_[4] = {v4.x,v4.y,v4.z,v4.w};
#pragma unroll
            for (int i = 0; i < 4; ++i)
#pragma unroll
                for (int j = 0; j < 4; ++j)
                    acc[i][j] = fmaf(a_[i], v_[j], acc[i][j]);
        }
        __syncthreads();
    }
    const long kvbase = ((long)chunk * BH_ + bh) * 4096;
#pragma unroll
    for (int i = 0; i < 4; ++i) {
        float4 o = {acc[i][0], acc[i][1], acc[i][2], acc[i][3]};
        *(float4*)(kvp + kvbase + (ty*4+i) * 64 + tx*4) = o;
    }
    if (t < 64) ksump[((long)chunk * BH_ + bh) * 64 + t] = ks;
}

// reduce partials; write kv as TRANSPOSED split-bf16 [BH][d][m] + ksum fp32 (+kvM fp32 for fallback)
__global__ __launch_bounds__(256) void kv_reduce(const float* __restrict__ kvp,
                                                 const float* __restrict__ ksump,
                                                 float* __restrict__ kvM,
                                                 float* __restrict__ ksum,
                                                 unsigned short* __restrict__ kvThi,
                                                 unsigned short* __restrict__ kvTlo)
{
    int idx = blockIdx.x * 256 + threadIdx.x;
    if (idx < BH_ * 4096) {
        float s = 0.f;
#pragma unroll
        for (int c = 0; c < SPLITK; ++c) s += kvp[(long)c * BH_ * 4096 + idx];
        kvM[idx] = s;
        int bh = idx >> 12, md = idx & 4095, m = md >> 6, d = md & 63;
        unsigned short h16 = f32_to_bf16(s);
        long toff = (long)bh * 4096 + d * 64 + m;
        kvThi[toff] = h16;
        kvTlo[toff] = f32_to_bf16(s - bf16_to_f32(h16));
    } else {
        int j = idx - BH_ * 4096;
        if (j < BH_ * 64) {
            float s = 0.f;
#pragma unroll
            for (int c = 0; c < SPLITK; ++c) s += ksump[(long)c * BH_ * 64 + j];
            ksum[j] = s;
        }
    }
}

// ---------------- qkv + normalize (fallback only) ----------------
__global__ __launch_bounds__(256) void qkv_attn(const float* __restrict__ Qp,
                                                const float* __restrict__ kvM,
                                                const float* __restrict__ ksum,
                                                float* __restrict__ attn)
{
    __shared__ float QPs[64][68];
    __shared__ float kvs[64][68];
    __shared__ float ksums[64];
    __shared__ float rnorm[64];
    const int bh = blockIdx.x, b = bh >> 4, h = bh & 15;
    const int n0 = blockIdx.y * 64;
    const int t = threadIdx.x;
    const int r = t >> 2, c0 = (t & 3) * 16;
    const int ty = t >> 4, tx = t & 15;

#pragma unroll
    for (int c = 0; c < 4; ++c) {
        int idx = t * 16 + c * 4;
        float4 v = *(const float4*)(kvM + (long)bh * 4096 + idx);
        *(float4*)&kvs[idx >> 6][idx & 63] = v;
    }
    if (t < 64) ksums[t] = ksum[bh * 64 + t];
    const float* qrow = Qp + (long)(b * N_ + n0 + r) * E_ + h * 64;
#pragma unroll
    for (int c = 0; c < 4; ++c) {
        float4 v = *(const float4*)(qrow + c0 + c*4);
        QPs[c0+c*4+0][r] = v.x; QPs[c0+c*4+1][r] = v.y; QPs[c0+c*4+2][r] = v.z; QPs[c0+c*4+3][r] = v.w;
    }
    __syncthreads();
    if (t < 64) {
        float s = 0.f;
#pragma unroll 16
        for (int m = 0; m < 64; ++m) s = fmaf(QPs[m][t], ksums[m], s);
        rnorm[t] = 1.f / fmaxf(s, EPSD);
    }
    __syncthreads();
    float acc[4][4] = {};
#pragma unroll 16
    for (int m = 0; m < 64; ++m) {
        float4 a = *(const float4*)&QPs[m][ty*4];
        float4 v4 = *(const float4*)&kvs[m][tx*4];
        float a_[4] = {a.x,a.y,a.z,a.w};
        float v_[4] = {v4.x,v4.y,v4.z,v4.w};
#pragma unroll
        for (int i = 0; i < 4; ++i)
#pragma unroll
            for (int j = 0; j < 4; ++j)
                acc[i][j] = fmaf(a_[i], v_[j], acc[i][j]);
    }
#pragma unroll
    for (int i = 0; i < 4; ++i) {
        int row = ty*4 + i;
        float rn = rnorm[row];
        float4 o = {acc[i][0]*rn, acc[i][1]*rn, acc[i][2]*rn, acc[i][3]*rn};
        *(float4*)(attn + (long)(b * N_ + n0 + row) * E_ + h * 64 + tx*4) = o;
    }
}

extern "C" void kernel_launch(void* const* d_in, const int* in_sizes, int n_in,
                              void* d_out, int out_size, void* d_ws, size_t ws_size,
                              hipStream_t stream)
{
    const float* query = (const float*)d_in[0];
    const float* key   = (const float*)d_in[1];
    const float* value = (const float*)d_in[2];
    const float* Wq    = (const float*)d_in[3];
    const float* bq    = (const float*)d_in[4];
    const float* Wk    = (const float*)d_in[5];
    const float* bk    = (const float*)d_in[6];
    const float* Wv    = (const float*)d_in[7];
    const float* bv    = (const float*)d_in[8];
    const float* Wo    = (const float*)d_in[9];
    const float* bo    = (const float*)d_in[10];
    const float* proj  = (const float*)d_in[11];
    float* O = (float*)d_out;                 // scratch (T1 / fallback interm.); fully rewritten at end

    float* ws = (float*)d_ws;
    const size_t SZ = (size_t)BN_ * E_;       // 16.78M floats
    float* A     = ws;                        // V fp32; later attn (split-bf16 in fast path)
    float* kvp   = ws + SZ;
    float* ksump = kvp + (size_t)SPLITK * BH_ * 4096;
    float* kvM   = ksump + (size_t)SPLITK * BH_ * 64;
    float* ksum  = kvM + (size_t)BH_ * 4096;
    float* stab  = ksum + (size_t)BH_ * 64;
    unsigned short* kvThi = (unsigned short*)(stab + 64);            // BH*4096 ush
    unsigned short* kvTlo = kvThi + (size_t)BH_ * 4096;
    unsigned short* PShi  = kvTlo + (size_t)BH_ * 4096;              // 65536 ush
    unsigned short* PSlo  = PShi + 65536;
    // align next region to float boundary
    const size_t COMMON = SZ + (size_t)SPLITK * BH_ * 4096 + (size_t)SPLITK * BH_ * 64
                        + (size_t)BH_ * 4096 + (size_t)BH_ * 64 + 64
                        + ((size_t)BH_ * 4096) /*kvT pair as floats*/ + 65536 / 2 * 2 / 2 * 0 + 32768 * 2 / 2;
    // (kvThi+kvTlo = BH*8192 ush = BH*4096 floats; PShi+PSlo = 131072 ush = 65536 floats... recompute cleanly:)
    const size_t EXTRA_F = (size_t)BH_ * 4096 /*kvT pair*/ + 65536 /*PS pair*/;
    const size_t COMMON_F = SZ + (size_t)SPLITK * BH_ * 4096 + (size_t)SPLITK * BH_ * 64
                          + (size_t)BH_ * 4096 + (size_t)BH_ * 64 + 64 + EXTRA_F;
    unsigned short* Xhi = (unsigned short*)(ws + COMMON_F);
    unsigned short* Xlo = Xhi + SZ;
    unsigned short* Whi = Xlo + SZ;
    unsigned short* Wlo = Whi + (size_t)E_ * E_;
    const size_t NEED_FAST = (COMMON_F + SZ + (size_t)E_ * E_) * 4;  // bytes
    (void)COMMON;

    dim3 gF(BH_, N_ / 64);
    dim3 gKV(BH_, SPLITK);
    const int nRed = (BH_ * 4096 + BH_ * 64) / 256;

    if (ws_size >= NEED_FAST) {
        dim3 gG(BN_ / 128, E_ / 128);
        const int X4 = (int)(SZ / 4), W4 = (E_ * E_) / 4;
        unsigned short* AttnHi = (unsigned short*)A;
        unsigned short* AttnLo = AttnHi + SZ;

        convert_split<1><<<64, 256, 0, stream>>>(proj, PShi, PSlo, 16384);
        init_stab<<<1, 64, 0, stream>>>(stab);
        // K chain: GEMM + fused favorp_k -> T1 (O) + stab
        convert_split<0><<<2048, 256, 0, stream>>>(key, Xhi, Xlo, X4);
        convert_split<1><<<1024, 256, 0, stream>>>(Wk, Whi, Wlo, W4);
        gemm_mfma<2><<<gG, 256, 0, stream>>>(Xhi, Xlo, Whi, Wlo, bk, O, stab,
                                             PShi, PSlo, nullptr, nullptr, nullptr, nullptr, nullptr);
        // V chain
        convert_split<0><<<2048, 256, 0, stream>>>(value, Xhi, Xlo, X4);
        convert_split<1><<<1024, 256, 0, stream>>>(Wv, Whi, Wlo, W4);
        gemm_mfma<0><<<gG, 256, 0, stream>>>(Xhi, Xlo, Whi, Wlo, bv, A, nullptr,
                                             nullptr, nullptr, nullptr, nullptr, nullptr, nullptr, nullptr);
        // kv
        kv_partial<<<gKV, 256, 0, stream>>>(O, A, stab, kvp, ksump);
        kv_reduce<<<nRed, 256, 0, stream>>>(kvp, ksump, kvM, ksum, kvThi, kvTlo);
        // Q chain: GEMM + fused favorp_q + qkv -> attn split-bf16 (A region)
        convert_split<0><<<2048, 256, 0, stream>>>(query, Xhi, Xlo, X4);
        convert_split<1><<<1024, 256, 0, stream>>>(Wq, Whi, Wlo, W4);
        gemm_mfma<3><<<gG, 256, 0, stream>>>(Xhi, Xlo, Whi, Wlo, bq, nullptr, nullptr,
                                             PShi, PSlo, kvThi, kvTlo, ksum, AttnHi, AttnLo);
        // output GEMM
        convert_split<1><<<1024, 256, 0, stream>>>(Wo, Whi, Wlo, W4);
        gemm_mfma<1><<<gG, 256, 0, stream>>>(AttnHi, AttnLo, Whi, Wlo, bo, O, nullptr,
                                             nullptr, nullptr, nullptr, nullptr, nullptr, nullptr, nullptr);
    } else {
        // fp32 fallback (round-2 proven path)
        dim3 gGemm(BN_ / 64, E_ / 64);
        lin_gemm<0,0><<<gGemm, 256, 0, stream>>>(key, Wk, bk, O);
        init_stab<<<1, 64, 0, stream>>>(stab);
        favorp_dash<0><<<gF, 256, 0, stream>>>(O, proj, stab);
        lin_gemm<0,0><<<gGemm, 256, 0, stream>>>(value, Wv, bv, A);
        kv_partial<<<gKV, 256, 0, stream>>>(O, A, stab, kvp, ksump);
        kv_reduce<<<nRed, 256, 0, stream>>>(kvp, ksump, kvM, ksum, kvThi, kvTlo);
        lin_gemm<0,0><<<gGemm, 256, 0, stream>>>(query, Wq, bq, O);
        favorp_dash<1><<<gF, 256, 0, stream>>>(O, proj, stab);
        qkv_attn<<<gF, 256, 0, stream>>>(O, kvM, ksum, A);
        lin_gemm<1,1><<<gGemm, 256, 0, stream>>>(A, Wo, bo, O);
    }
}

// Round 5
// 618.148 us; speedup vs baseline: 3.2410x; 1.0116x over previous
//
#include <hip/hip_runtime.h>
#include <math.h>

// Problem constants (fixed by setup_inputs)
#define B_   4
#define N_   4096
#define E_   1024
#define H_   16
#define BN_  (B_*N_)
#define BH_  (B_*H_)
#define SPLITK 8

// favorp constants
#define NRM_C   0.35355339059327373f   // 64^-0.25
#define DIAG_C  0.0625f                // 0.5 * NRM^2
#define RATIO_C 0.125f                 // 64^-0.5
#define EPSF    1e-4f
#define EPSD    0.01f

typedef __attribute__((ext_vector_type(8))) short bf16x8;   // 8 bf16 in 4 VGPRs
typedef __attribute__((ext_vector_type(4))) float f32x4;

__device__ __forceinline__ unsigned short f32_to_bf16(float x) {
    unsigned int u = __float_as_uint(x);
    unsigned int r = (u + 0x7fffu + ((u >> 16) & 1u)) >> 16;   // RTN-even
    return (unsigned short)r;
}
__device__ __forceinline__ float bf16_to_f32(unsigned short h) {
    return __uint_as_float(((unsigned int)h) << 16);
}

__device__ __forceinline__ void atomicMaxF(float* addr, float v) {
    if (v >= 0.f) atomicMax((int*)addr, __float_as_int(v));
    else          atomicMin((unsigned int*)addr, __float_as_uint(v));
}

__global__ void init_stab(float* stab) {
    if (threadIdx.x < BH_) stab[threadIdx.x] = -INFINITY;
}

// ---------------- split-bf16 conversion ----------------
template<int IN_MODE>
__global__ __launch_bounds__(256) void convert_split(const float* __restrict__ src,
                                                     unsigned short* __restrict__ hi,
                                                     unsigned short* __restrict__ lo,
                                                     int total4)
{
    int i = blockIdx.x * 256 + threadIdx.x;
    const int stride = gridDim.x * 256;
    for (; i < total4; i += stride) {
        long e4 = (long)i * 4;
        const float* p;
        if (IN_MODE == 0) {
            long r = e4 >> 10; int e = (int)(e4 & 1023);
            int b = (int)(r >> 12), n = (int)(r & 4095);
            p = src + (((long)(n * B_ + b)) << 10) + e;
        } else {
            p = src + e4;
        }
        float4 v = *(const float4*)p;
        ushort4 h, l;
        h.x = f32_to_bf16(v.x); l.x = f32_to_bf16(v.x - bf16_to_f32(h.x));
        h.y = f32_to_bf16(v.y); l.y = f32_to_bf16(v.y - bf16_to_f32(h.y));
        h.z = f32_to_bf16(v.z); l.z = f32_to_bf16(v.z - bf16_to_f32(h.z));
        h.w = f32_to_bf16(v.w); l.w = f32_to_bf16(v.w - bf16_to_f32(h.w));
        *(ushort4*)(hi + e4) = h;
        *(ushort4*)(lo + e4) = l;
    }
}

__device__ __forceinline__ void gl_lds16(const unsigned short* g, unsigned short* l) {
    __builtin_amdgcn_global_load_lds((const __attribute__((address_space(1))) void*)g,
                                     (__attribute__((address_space(3))) void*)l, 16, 0, 0);
}

// ---------------- 8-wave 256x128 counted-vmcnt MFMA split-bf16 GEMM ----------------
// MODE 0: Y fp32 [BN,E]; MODE 1: Y fp32 [N,B,E]; MODE 2: K-fused favorp (T1 + stab);
// MODE 3: Q-fused favorp_q + qkv + normalize -> attn split-bf16.
// LDS: 3 buffers x (Ahi 16K | Alo 16K | Bhi 8K | Blo 8K) = 147456 B dynamic.
#define SMEM_DYN 147456

template<int MODE>
__global__ __launch_bounds__(512, 2) void gemm8(const unsigned short* __restrict__ Ahi,
                                                const unsigned short* __restrict__ Alo,
                                                const unsigned short* __restrict__ Bhi,
                                                const unsigned short* __restrict__ Blo,
                                                const float* __restrict__ bias,
                                                float* __restrict__ Y,
                                                float* __restrict__ stab,
                                                const unsigned short* __restrict__ PShi,
                                                const unsigned short* __restrict__ PSlo,
                                                const unsigned short* __restrict__ kvThi,
                                                const unsigned short* __restrict__ kvTlo,
                                                const float* __restrict__ ksum,
                                                unsigned short* __restrict__ AttnHi,
                                                unsigned short* __restrict__ AttnLo)
{
    extern __shared__ char SMEMc[];
    unsigned short* U = (unsigned short*)SMEMc;
    const int t = threadIdx.x;
    const int ww = t >> 6, lane = t & 63;
    const int row0 = blockIdx.x * 256, col0 = blockIdx.y * 128;
    const int w = ww;
    const int wrow = (w >> 1) * 64, wcol = (w & 1) * 64;
    const int g = lane >> 4, rl = lane & 15;

    f32x4 acc[4][4];
#pragma unroll
    for (int m = 0; m < 4; ++m)
#pragma unroll
        for (int n = 0; n < 4; ++n) acc[m][n] = (f32x4){0.f, 0.f, 0.f, 0.f};

    // stage tile TILE into buffer BUFI: A 2 chunks hi/lo + B 1 chunk hi/lo (6 loads/thread)
#define STAGE8(TILE, BUFI)                                                              \
    {                                                                                   \
        const int k0_ = (TILE) * 32;                                                    \
        unsigned short* bu_ = U + (BUFI) * 24576;                                       \
        int r0_ = t >> 2, s0_ = t & 3;                                                  \
        long soA0_ = (long)(row0 + r0_) * E_ + k0_ + ((s0_ ^ (r0_ & 3)) << 3);          \
        gl_lds16(Ahi + soA0_, bu_ + (ww * 64) * 8);                                     \
        gl_lds16(Alo + soA0_, bu_ + 8192 + (ww * 64) * 8);                              \
        int slot1_ = t + 512;                                                           \
        int r1_ = slot1_ >> 2, s1_ = slot1_ & 3;                                        \
        long soA1_ = (long)(row0 + r1_) * E_ + k0_ + ((s1_ ^ (r1_ & 3)) << 3);          \
        gl_lds16(Ahi + soA1_, bu_ + (512 + ww * 64) * 8);                               \
        gl_lds16(Alo + soA1_, bu_ + 8192 + (512 + ww * 64) * 8);                        \
        long soB_ = (long)(col0 + r0_) * E_ + k0_ + ((s0_ ^ (r0_ & 3)) << 3);           \
        gl_lds16(Bhi + soB_, bu_ + 16384 + (ww * 64) * 8);                              \
        gl_lds16(Blo + soB_, bu_ + 20480 + (ww * 64) * 8);                              \
    }

#define COMPUTE8(BUFI)                                                                  \
    {                                                                                   \
        const unsigned short* sb_ = U + (BUFI) * 24576;                                 \
        bf16x8 ah[4], al[4], bhf[4], blf[4];                                            \
        _Pragma("unroll")                                                               \
        for (int m = 0; m < 4; ++m) {                                                   \
            int r_ = wrow + m * 16 + rl;                                                \
            int off_ = r_ * 32 + ((g ^ (r_ & 3)) << 3);                                 \
            ah[m] = *(const bf16x8*)(sb_ + off_);                                       \
            al[m] = *(const bf16x8*)(sb_ + 8192 + off_);                                \
        }                                                                               \
        _Pragma("unroll")                                                               \
        for (int n = 0; n < 4; ++n) {                                                   \
            int r_ = wcol + n * 16 + rl;                                                \
            int off_ = r_ * 32 + ((g ^ (r_ & 3)) << 3);                                 \
            bhf[n] = *(const bf16x8*)(sb_ + 16384 + off_);                              \
            blf[n] = *(const bf16x8*)(sb_ + 20480 + off_);                              \
        }                                                                               \
        _Pragma("unroll")                                                               \
        for (int m = 0; m < 4; ++m)                                                     \
            _Pragma("unroll")                                                           \
            for (int n = 0; n < 4; ++n)                                                 \
                acc[m][n] = __builtin_amdgcn_mfma_f32_16x16x32_bf16(ah[m], bhf[n], acc[m][n], 0, 0, 0); \
        _Pragma("unroll")                                                               \
        for (int m = 0; m < 4; ++m)                                                     \
            _Pragma("unroll")                                                           \
            for (int n = 0; n < 4; ++n)                                                 \
                acc[m][n] = __builtin_amdgcn_mfma_f32_16x16x32_bf16(ah[m], blf[n], acc[m][n], 0, 0, 0); \
        _Pragma("unroll")                                                               \
        for (int m = 0; m < 4; ++m)                                                     \
            _Pragma("unroll")                                                           \
            for (int n = 0; n < 4; ++n)                                                 \
                acc[m][n] = __builtin_amdgcn_mfma_f32_16x16x32_bf16(al[m], bhf[n], acc[m][n], 0, 0, 0); \
    }

    STAGE8(0, 0);
    STAGE8(1, 1);
    int rb = 0, sbuf = 2;
    for (int tt = 0; tt < 31; ++tt) {
        asm volatile("s_waitcnt vmcnt(6)" ::: "memory");
        __builtin_amdgcn_s_barrier();
        __builtin_amdgcn_sched_barrier(0);
        if (tt < 30) { STAGE8(tt + 2, sbuf); }
        COMPUTE8(rb);
        rb = (rb + 1 == 3) ? 0 : rb + 1;
        sbuf = (sbuf + 1 == 3) ? 0 : sbuf + 1;
    }
    asm volatile("s_waitcnt vmcnt(0)" ::: "memory");
    __builtin_amdgcn_s_barrier();
    __builtin_amdgcn_sched_barrier(0);
    COMPUTE8(1);
#undef STAGE8
#undef COMPUTE8

    float bv[4];
#pragma unroll
    for (int n = 0; n < 4; ++n) bv[n] = bias[col0 + wcol + n * 16 + rl];

    if (MODE <= 1) {
        // plain epilogue: C/D layout col = lane&15, row = (lane>>4)*4 + reg
#pragma unroll
        for (int m = 0; m < 4; ++m) {
            int rbase = row0 + wrow + m * 16 + g * 4;
#pragma unroll
            for (int n = 0; n < 4; ++n) {
                int c = col0 + wcol + n * 16 + rl;
#pragma unroll
                for (int q = 0; q < 4; ++q) {
                    int r = rbase + q;
                    float v = acc[m][n][q] + bv[n];
                    long off;
                    if (MODE == 0) off = (long)r * E_ + c;
                    else { int b = r >> 12, nn = r & (N_ - 1); off = (long)(nn * B_ + b) * E_ + c; }
                    Y[off] = v;
                }
            }
        }
        return;
    }

    // ---------------- fused favorp epilogue (MODE 2 / 3) ----------------
    __syncthreads();   // all waves done with staging LDS; SMEM reusable
    float* accF  = (float*)SMEMc + w * (64 * 68);              // wave-private [64][68]
    float* diagL = (float*)(SMEMc + 139264) + w * 64;
    float* rnmL  = (float*)(SMEMc + 139264 + 2048) + w * 64;
    const int b_idx = row0 >> 12;
    const int hg = (col0 >> 6) + (w & 1);                      // global head 0..15
    const int bh = b_idx * H_ + hg;

#pragma unroll
    for (int m = 0; m < 4; ++m)
#pragma unroll
        for (int n = 0; n < 4; ++n)
#pragma unroll
            for (int q = 0; q < 4; ++q)
                accF[(m*16 + g*4 + q) * 68 + n*16 + rl] = acc[m][n][q] + bv[n];
    {
        float s = 0.f;
#pragma unroll 16
        for (int d = 0; d < 64; ++d) { float x = accF[lane * 68 + d]; s = fmaf(x, x, s); }
        diagL[lane] = s * DIAG_C;
    }
    __syncthreads();

    float wavemax = -INFINITY;
#pragma unroll
    for (int mi = 0; mi < 4; ++mi) {
        bf16x8 dah[2], dal[2];
#pragma unroll
        for (int kk = 0; kk < 2; ++kk) {
            const float* src = &accF[(mi*16 + rl) * 68 + kk*32 + g*8];
            float4 f0 = *(const float4*)src, f1 = *(const float4*)(src + 4);
            float fv[8] = {f0.x,f0.y,f0.z,f0.w,f1.x,f1.y,f1.z,f1.w};
            bf16x8 hh, ll;
#pragma unroll
            for (int j = 0; j < 8; ++j) {
                unsigned short h16 = f32_to_bf16(fv[j]);
                hh[j] = (short)h16;
                ll[j] = (short)f32_to_bf16(fv[j] - bf16_to_f32(h16));
            }
            dah[kk] = hh; dal[kk] = ll;
        }
        f32x4 dacc[4];
#pragma unroll
        for (int n = 0; n < 4; ++n) dacc[n] = (f32x4){0.f,0.f,0.f,0.f};
#pragma unroll
        for (int n = 0; n < 4; ++n)
#pragma unroll
            for (int kk = 0; kk < 2; ++kk) {
                long po = (long)hg * 4096 + (n*16 + rl) * 64 + kk*32 + g*8;
                bf16x8 pbh = *(const bf16x8*)(PShi + po);
                bf16x8 pbl = *(const bf16x8*)(PSlo + po);
                dacc[n] = __builtin_amdgcn_mfma_f32_16x16x32_bf16(dah[kk], pbh, dacc[n], 0, 0, 0);
                dacc[n] = __builtin_amdgcn_mfma_f32_16x16x32_bf16(dah[kk], pbl, dacc[n], 0, 0, 0);
                dacc[n] = __builtin_amdgcn_mfma_f32_16x16x32_bf16(dal[kk], pbh, dacc[n], 0, 0, 0);
            }
        if (MODE == 2) {
#pragma unroll
            for (int n = 0; n < 4; ++n)
#pragma unroll
                for (int q = 0; q < 4; ++q) {
                    float dsh = dacc[n][q] * NRM_C;
                    wavemax = fmaxf(wavemax, dsh);
                    int rloc = mi*16 + g*4 + q;
                    Y[(long)(row0 + wrow + rloc) * E_ + col0 + wcol + n*16 + rl] = dsh - diagL[rloc];
                }
        } else {
            float rm0 = -INFINITY, rm1 = -INFINITY, rm2 = -INFINITY, rm3 = -INFINITY;
#pragma unroll
            for (int n = 0; n < 4; ++n) {
                rm0 = fmaxf(rm0, dacc[n][0]); rm1 = fmaxf(rm1, dacc[n][1]);
                rm2 = fmaxf(rm2, dacc[n][2]); rm3 = fmaxf(rm3, dacc[n][3]);
            }
#pragma unroll
            for (int off = 1; off < 16; off <<= 1) {
                rm0 = fmaxf(rm0, __shfl_xor(rm0, off));
                rm1 = fmaxf(rm1, __shfl_xor(rm1, off));
                rm2 = fmaxf(rm2, __shfl_xor(rm2, off));
                rm3 = fmaxf(rm3, __shfl_xor(rm3, off));
            }
            float rmq[4] = {rm0 * NRM_C, rm1 * NRM_C, rm2 * NRM_C, rm3 * NRM_C};
#pragma unroll
            for (int n = 0; n < 4; ++n)
#pragma unroll
                for (int q = 0; q < 4; ++q) {
                    int rloc = mi*16 + g*4 + q;
                    float qp = RATIO_C * expf(dacc[n][q] * NRM_C - diagL[rloc] - rmq[q]) + EPSF;
                    accF[rloc * 68 + n*16 + rl] = qp;
                }
        }
    }

    if (MODE == 2) {
#pragma unroll
        for (int off = 1; off < 64; off <<= 1) wavemax = fmaxf(wavemax, __shfl_xor(wavemax, off));
        if (lane == 0) atomicMaxF(&stab[bh], wavemax);
        return;
    }

    // MODE 3: normalizer, then qkv via MFMA against kvT
    {
        float s = 0.f;
        const float* kb = ksum + bh * 64;
#pragma unroll 16
        for (int m = 0; m < 64; ++m) s = fmaf(accF[lane * 68 + m], kb[m], s);
        rnmL[lane] = 1.f / fmaxf(s, EPSD);
    }
    __syncthreads();
#pragma unroll
    for (int mi = 0; mi < 4; ++mi) {
        bf16x8 qah[2], qal[2];
#pragma unroll
        for (int kk = 0; kk < 2; ++kk) {
            const float* src = &accF[(mi*16 + rl) * 68 + kk*32 + g*8];
            float4 f0 = *(const float4*)src, f1 = *(const float4*)(src + 4);
            float fv[8] = {f0.x,f0.y,f0.z,f0.w,f1.x,f1.y,f1.z,f1.w};
            bf16x8 hh, ll;
#pragma unroll
            for (int j = 0; j < 8; ++j) {
                unsigned short h16 = f32_to_bf16(fv[j]);
                hh[j] = (short)h16;
                ll[j] = (short)f32_to_bf16(fv[j] - bf16_to_f32(h16));
            }
            qah[kk] = hh; qal[kk] = ll;
        }
        f32x4 oacc[4];
#pragma unroll
        for (int n = 0; n < 4; ++n) oacc[n] = (f32x4){0.f,0.f,0.f,0.f};
#pragma unroll
        for (int n = 0; n < 4; ++n)
#pragma unroll
            for (int kk = 0; kk < 2; ++kk) {
                long ko = (long)bh * 4096 + (n*16 + rl) * 64 + kk*32 + g*8;
                bf16x8 kbh = *(const bf16x8*)(kvThi + ko);
                bf16x8 kbl = *(const bf16x8*)(kvTlo + ko);
                oacc[n] = __builtin_amdgcn_mfma_f32_16x16x32_bf16(qah[kk], kbh, oacc[n], 0, 0, 0);
                oacc[n] = __builtin_amdgcn_mfma_f32_16x16x32_bf16(qah[kk], kbl, oacc[n], 0, 0, 0);
                oacc[n] = __builtin_amdgcn_mfma_f32_16x16x32_bf16(qal[kk], kbh, oacc[n], 0, 0, 0);
            }
#pragma unroll
        for (int n = 0; n < 4; ++n)
#pragma unroll
            for (int q = 0; q < 4; ++q) {
                int rloc = mi*16 + g*4 + q;
                float o = oacc[n][q] * rnmL[rloc];
                long off = (long)(row0 + wrow + rloc) * E_ + col0 + wcol + n*16 + rl;
                unsigned short h16 = f32_to_bf16(o);
                AttnHi[off] = h16;
                AttnLo[off] = f32_to_bf16(o - bf16_to_f32(h16));
            }
    }
}

// ---------------- fp32 fallback GEMM (round-2 proven) ----------------
template<int IN_MODE, int OUT_MODE>
__global__ __launch_bounds__(256) void lin_gemm(const float* __restrict__ X,
                                                const float* __restrict__ W,
                                                const float* __restrict__ bias,
                                                float* __restrict__ Y)
{
    __shared__ float As[16][68];
    __shared__ float Ws[16][68];
    const int row0 = blockIdx.x * 64;
    const int col0 = blockIdx.y * 64;
    const int t  = threadIdx.x;
    const int lr = t >> 2;
    const int lk = (t & 3) * 4;
    const int ty = t >> 4, tx = t & 15;

    long arow;
    {
        int r = row0 + lr;
        if (IN_MODE == 0) { int b = r >> 12, n = r & (N_ - 1); arow = (long)(n * B_ + b) * E_; }
        else              { arow = (long)r * E_; }
    }
    const long wrow = (long)(col0 + lr) * E_;

    float acc[4][4] = {};
    for (int e0 = 0; e0 < E_; e0 += 16) {
        float4 av = *(const float4*)(X + arow + e0 + lk);
        float4 wv = *(const float4*)(W + wrow + e0 + lk);
        As[lk+0][lr] = av.x; As[lk+1][lr] = av.y; As[lk+2][lr] = av.z; As[lk+3][lr] = av.w;
        Ws[lk+0][lr] = wv.x; Ws[lk+1][lr] = wv.y; Ws[lk+2][lr] = wv.z; Ws[lk+3][lr] = wv.w;
        __syncthreads();
#pragma unroll
        for (int k = 0; k < 16; ++k) {
            float4 a = *(const float4*)&As[k][ty*4];
            float4 w = *(const float4*)&Ws[k][tx*4];
            float a_[4] = {a.x,a.y,a.z,a.w};
            float w_[4] = {w.x,w.y,w.z,w.w};
#pragma unroll
            for (int i = 0; i < 4; ++i)
#pragma unroll
                for (int j = 0; j < 4; ++j)
                    acc[i][j] = fmaf(a_[i], w_[j], acc[i][j]);
        }
        __syncthreads();
    }
    float4 bvv = *(const float4*)(bias + col0 + tx*4);
    float b_[4] = {bvv.x,bvv.y,bvv.z,bvv.w};
#pragma unroll
    for (int i = 0; i < 4; ++i) {
        int r = row0 + ty*4 + i;
        float4 o;
        o.x = acc[i][0] + b_[0]; o.y = acc[i][1] + b_[1];
        o.z = acc[i][2] + b_[2]; o.w = acc[i][3] + b_[3];
        long off;
        if (OUT_MODE == 0) off = (long)r * E_ + col0 + tx*4;
        else { int b = r >> 12, n = r & (N_ - 1); off = (long)(n * B_ + b) * E_ + col0 + tx*4; }
        *(float4*)(Y + off) = o;
    }
}

// ---------------- favorp dash (fallback, IN-PLACE over [B,N,E]) ----------------
template<int IS_QUERY>
__global__ __launch_bounds__(256) void favorp_dash(float* __restrict__ Xh,
                                                   const float* __restrict__ proj,
                                                   float* __restrict__ stab)
{
    __shared__ float Xs[64][68];
    __shared__ float Ps[64][68];
    __shared__ float diag[64];
    __shared__ float red4[4];
    __shared__ float rowred[64][17];
    const int bh = blockIdx.x, b = bh >> 4, h = bh & 15;
    const int n0 = blockIdx.y * 64;
    const int t = threadIdx.x;
    const int r = t >> 2, c0 = (t & 3) * 16;
    const int ty = t >> 4, tx = t & 15;

    const float* xrow = Xh + (long)(b * N_ + n0 + r) * E_ + h * 64;
    const float* prow = proj + (long)(h * 64 + r) * 64;
#pragma unroll
    for (int c = 0; c < 4; ++c) {
        float4 v = *(const float4*)(xrow + c0 + c*4);
        Xs[c0+c*4+0][r] = v.x; Xs[c0+c*4+1][r] = v.y; Xs[c0+c*4+2][r] = v.z; Xs[c0+c*4+3][r] = v.w;
        float4 p = *(const float4*)(prow + c0 + c*4);
        Ps[c0+c*4+0][r] = p.x; Ps[c0+c*4+1][r] = p.y; Ps[c0+c*4+2][r] = p.z; Ps[c0+c*4+3][r] = p.w;
    }
    __syncthreads();
    if (t < 64) {
        float s = 0.f;
#pragma unroll 16
        for (int d = 0; d < 64; ++d) { float x = Xs[d][t]; s = fmaf(x, x, s); }
        diag[t] = s * DIAG_C;
    }
    __syncthreads();

    float acc[4][4] = {};
#pragma unroll 16
    for (int d = 0; d < 64; ++d) {
        float4 a = *(const float4*)&Xs[d][ty*4];
        float4 p = *(const float4*)&Ps[d][tx*4];
        float a_[4] = {a.x,a.y,a.z,a.w};
        float p_[4] = {p.x,p.y,p.z,p.w};
#pragma unroll
        for (int i = 0; i < 4; ++i)
#pragma unroll
            for (int j = 0; j < 4; ++j)
                acc[i][j] = fmaf(a_[i], p_[j], acc[i][j]);
    }
    float dash[4][4];
#pragma unroll
    for (int i = 0; i < 4; ++i)
#pragma unroll
        for (int j = 0; j < 4; ++j) dash[i][j] = acc[i][j] * NRM_C;

    if (IS_QUERY) {
#pragma unroll
        for (int i = 0; i < 4; ++i) {
            float m = fmaxf(fmaxf(dash[i][0], dash[i][1]), fmaxf(dash[i][2], dash[i][3]));
            rowred[ty*4+i][tx] = m;
        }
        __syncthreads();
#pragma unroll
        for (int i = 0; i < 4; ++i) {
            int row = ty*4 + i;
            float m = rowred[row][0];
#pragma unroll
            for (int jj = 1; jj < 16; ++jj) m = fmaxf(m, rowred[row][jj]);
            float dg = diag[row];
            float4 o;
            o.x = RATIO_C * expf(dash[i][0] - dg - m) + EPSF;
            o.y = RATIO_C * expf(dash[i][1] - dg - m) + EPSF;
            o.z = RATIO_C * expf(dash[i][2] - dg - m) + EPSF;
            o.w = RATIO_C * expf(dash[i][3] - dg - m) + EPSF;
            *(float4*)(Xh + (long)(b * N_ + n0 + row) * E_ + h * 64 + tx*4) = o;
        }
    } else {
        float lmax = dash[0][0];
#pragma unroll
        for (int i = 0; i < 4; ++i)
#pragma unroll
            for (int j = 0; j < 4; ++j) lmax = fmaxf(lmax, dash[i][j]);
#pragma unroll
        for (int i = 0; i < 4; ++i) {
            int row = ty*4 + i;
            float dg = diag[row];
            float4 o = { dash[i][0]-dg, dash[i][1]-dg, dash[i][2]-dg, dash[i][3]-dg };
            *(float4*)(Xh + (long)(b * N_ + n0 + row) * E_ + h * 64 + tx*4) = o;
        }
#pragma unroll
        for (int off = 32; off > 0; off >>= 1) lmax = fmaxf(lmax, __shfl_down(lmax, off));
        if ((t & 63) == 0) red4[t >> 6] = lmax;
        __syncthreads();
        if (t == 0)
            atomicMaxF(&stab[bh], fmaxf(fmaxf(red4[0], red4[1]), fmaxf(red4[2], red4[3])));
    }
}

// ---------------- kv partials ----------------
__global__ __launch_bounds__(256) void kv_partial(const float* __restrict__ T1,
                                                  const float* __restrict__ V,
                                                  const float* __restrict__ stab,
                                                  float* __restrict__ kvp,
                                                  float* __restrict__ ksump)
{
    __shared__ float KPs[16][68];
    __shared__ float Vs[16][68];
    const int bh = blockIdx.x, chunk = blockIdx.y;
    const int b = bh >> 4, h = bh & 15;
    const int t = threadIdx.x;
    const int lr = t >> 4, lm = (t & 15) * 4;
    const int ty = t >> 4, tx = t & 15;
    const float stb = stab[bh];
    float acc[4][4] = {};
    float ks = 0.f;
    const int nbeg = chunk * (N_ / SPLITK), nend = nbeg + (N_ / SPLITK);
    for (int n0 = nbeg; n0 < nend; n0 += 16) {
        long rowoff = (long)(b * N_ + n0 + lr) * E_ + h * 64 + lm;
        float4 tv = *(const float4*)(T1 + rowoff);
        float4 vv = *(const float4*)(V + rowoff);
        KPs[lr][lm+0] = RATIO_C * expf(tv.x - stb) + EPSF;
        KPs[lr][lm+1] = RATIO_C * expf(tv.y - stb) + EPSF;
        KPs[lr][lm+2] = RATIO_C * expf(tv.z - stb) + EPSF;
        KPs[lr][lm+3] = RATIO_C * expf(tv.w - stb) + EPSF;
        *(float4*)&Vs[lr][lm] = vv;
        __syncthreads();
        if (t < 64) {
#pragma unroll
            for (int rr = 0; rr < 16; ++rr) ks += KPs[rr][t];
        }
#pragma unroll
        for (int k = 0; k < 16; ++k) {
            float4 a = *(const float4*)&KPs[k][ty*4];
            float4 v4 = *(const float4*)&Vs[k][tx*4];
            float a_[4] = {a.x,a.y,a.z,a.w};
            float v_[4] = {v4.x,v4.y,v4.z,v4.w};
#pragma unroll
            for (int i = 0; i < 4; ++i)
#pragma unroll
                for (int j = 0; j < 4; ++j)
                    acc[i][j] = fmaf(a_[i], v_[j], acc[i][j]);
        }
        __syncthreads();
    }
    const long kvbase = ((long)chunk * BH_ + bh) * 4096;
#pragma unroll
    for (int i = 0; i < 4; ++i) {
        float4 o = {acc[i][0], acc[i][1], acc[i][2], acc[i][3]};
        *(float4*)(kvp + kvbase + (ty*4+i) * 64 + tx*4) = o;
    }
    if (t < 64) ksump[((long)chunk * BH_ + bh) * 64 + t] = ks;
}

// reduce partials; write kv TRANSPOSED split-bf16 [BH][d][m] + ksum fp32 (+kvM fp32 for fallback)
__global__ __launch_bounds__(256) void kv_reduce(const float* __restrict__ kvp,
                                                 const float* __restrict__ ksump,
                                                 float* __restrict__ kvM,
                                                 float* __restrict__ ksum,
                                                 unsigned short* __restrict__ kvThi,
                                                 unsigned short* __restrict__ kvTlo)
{
    int idx = blockIdx.x * 256 + threadIdx.x;
    if (idx < BH_ * 4096) {
        float s = 0.f;
#pragma unroll
        for (int c = 0; c < SPLITK; ++c) s += kvp[(long)c * BH_ * 4096 + idx];
        kvM[idx] = s;
        int bh = idx >> 12, md = idx & 4095, m = md >> 6, d = md & 63;
        unsigned short h16 = f32_to_bf16(s);
        long toff = (long)bh * 4096 + d * 64 + m;
        kvThi[toff] = h16;
        kvTlo[toff] = f32_to_bf16(s - bf16_to_f32(h16));
    } else {
        int j = idx - BH_ * 4096;
        if (j < BH_ * 64) {
            float s = 0.f;
#pragma unroll
            for (int c = 0; c < SPLITK; ++c) s += ksump[(long)c * BH_ * 64 + j];
            ksum[j] = s;
        }
    }
}

// ---------------- qkv + normalize (fallback only) ----------------
__global__ __launch_bounds__(256) void qkv_attn(const float* __restrict__ Qp,
                                                const float* __restrict__ kvM,
                                                const float* __restrict__ ksum,
                                                float* __restrict__ attn)
{
    __shared__ float QPs[64][68];
    __shared__ float kvs[64][68];
    __shared__ float ksums[64];
    __shared__ float rnorm[64];
    const int bh = blockIdx.x, b = bh >> 4, h = bh & 15;
    const int n0 = blockIdx.y * 64;
    const int t = threadIdx.x;
    const int r = t >> 2, c0 = (t & 3) * 16;
    const int ty = t >> 4, tx = t & 15;

#pragma unroll
    for (int c = 0; c < 4; ++c) {
        int idx = t * 16 + c * 4;
        float4 v = *(const float4*)(kvM + (long)bh * 4096 + idx);
        *(float4*)&kvs[idx >> 6][idx & 63] = v;
    }
    if (t < 64) ksums[t] = ksum[bh * 64 + t];
    const float* qrow = Qp + (long)(b * N_ + n0 + r) * E_ + h * 64;
#pragma unroll
    for (int c = 0; c < 4; ++c) {
        float4 v = *(const float4*)(qrow + c0 + c*4);
        QPs[c0+c*4+0][r] = v.x; QPs[c0+c*4+1][r] = v.y; QPs[c0+c*4+2][r] = v.z; QPs[c0+c*4+3][r] = v.w;
    }
    __syncthreads();
    if (t < 64) {
        float s = 0.f;
#pragma unroll 16
        for (int m = 0; m < 64; ++m) s = fmaf(QPs[m][t], ksums[m], s);
        rnorm[t] = 1.f / fmaxf(s, EPSD);
    }
    __syncthreads();
    float acc[4][4] = {};
#pragma unroll 16
    for (int m = 0; m < 64; ++m) {
        float4 a = *(const float4*)&QPs[m][ty*4];
        float4 v4 = *(const float4*)&kvs[m][tx*4];
        float a_[4] = {a.x,a.y,a.z,a.w};
        float v_[4] = {v4.x,v4.y,v4.z,v4.w};
#pragma unroll
        for (int i = 0; i < 4; ++i)
#pragma unroll
            for (int j = 0; j < 4; ++j)
                acc[i][j] = fmaf(a_[i], v_[j], acc[i][j]);
    }
#pragma unroll
    for (int i = 0; i < 4; ++i) {
        int row = ty*4 + i;
        float rn = rnorm[row];
        float4 o = {acc[i][0]*rn, acc[i][1]*rn, acc[i][2]*rn, acc[i][3]*rn};
        *(float4*)(attn + (long)(b * N_ + n0 + row) * E_ + h * 64 + tx*4) = o;
    }
}

extern "C" void kernel_launch(void* const* d_in, const int* in_sizes, int n_in,
                              void* d_out, int out_size, void* d_ws, size_t ws_size,
                              hipStream_t stream)
{
    const float* query = (const float*)d_in[0];
    const float* key   = (const float*)d_in[1];
    const float* value = (const float*)d_in[2];
    const float* Wq    = (const float*)d_in[3];
    const float* bq    = (const float*)d_in[4];
    const float* Wk    = (const float*)d_in[5];
    const float* bk    = (const float*)d_in[6];
    const float* Wv    = (const float*)d_in[7];
    const float* bv    = (const float*)d_in[8];
    const float* Wo    = (const float*)d_in[9];
    const float* bo    = (const float*)d_in[10];
    const float* proj  = (const float*)d_in[11];
    float* O = (float*)d_out;                 // scratch; fully rewritten by final GEMM

    float* ws = (float*)d_ws;
    const size_t SZ = (size_t)BN_ * E_;       // 16.78M floats
    float* A     = ws;                        // V fp32; later attn (split-bf16 in fast path)
    float* kvp   = ws + SZ;
    float* ksump = kvp + (size_t)SPLITK * BH_ * 4096;
    float* kvM   = ksump + (size_t)SPLITK * BH_ * 64;
    float* ksum  = kvM + (size_t)BH_ * 4096;
    float* stab  = ksum + (size_t)BH_ * 64;
    unsigned short* kvThi = (unsigned short*)(stab + 64);            // BH*4096 ush
    unsigned short* kvTlo = kvThi + (size_t)BH_ * 4096;
    unsigned short* PShi  = kvTlo + (size_t)BH_ * 4096;              // 65536 ush
    unsigned short* PSlo  = PShi + 65536;
    const size_t EXTRA_F = (size_t)BH_ * 4096 /*kvT pair*/ + 65536 /*PS pair*/;
    const size_t COMMON_F = SZ + (size_t)SPLITK * BH_ * 4096 + (size_t)SPLITK * BH_ * 64
                          + (size_t)BH_ * 4096 + (size_t)BH_ * 64 + 64 + EXTRA_F;
    unsigned short* Xhi = (unsigned short*)(ws + COMMON_F);
    unsigned short* Xlo = Xhi + SZ;
    unsigned short* Whi = Xlo + SZ;
    unsigned short* Wlo = Whi + (size_t)E_ * E_;
    const size_t NEED_FAST = (COMMON_F + SZ + (size_t)E_ * E_) * 4;  // bytes

    dim3 gF(BH_, N_ / 64);
    dim3 gKV(BH_, SPLITK);
    const int nRed = (BH_ * 4096 + BH_ * 64) / 256;

    if (ws_size >= NEED_FAST) {
        dim3 gG(BN_ / 256, E_ / 128);
        const int X4 = (int)(SZ / 4), W4 = (E_ * E_) / 4;
        unsigned short* AttnHi = (unsigned short*)A;
        unsigned short* AttnLo = AttnHi + SZ;

        // allow >64KB dynamic LDS (defensive; ignore errors)
        (void)hipFuncSetAttribute((const void*)&gemm8<0>, hipFuncAttributeMaxDynamicSharedMemorySize, SMEM_DYN);
        (void)hipFuncSetAttribute((const void*)&gemm8<1>, hipFuncAttributeMaxDynamicSharedMemorySize, SMEM_DYN);
        (void)hipFuncSetAttribute((const void*)&gemm8<2>, hipFuncAttributeMaxDynamicSharedMemorySize, SMEM_DYN);
        (void)hipFuncSetAttribute((const void*)&gemm8<3>, hipFuncAttributeMaxDynamicSharedMemorySize, SMEM_DYN);

        convert_split<1><<<64, 256, 0, stream>>>(proj, PShi, PSlo, 16384);
        init_stab<<<1, 64, 0, stream>>>(stab);
        // K chain: GEMM + fused favorp_k -> T1 (O) + stab
        convert_split<0><<<2048, 256, 0, stream>>>(key, Xhi, Xlo, X4);
        convert_split<1><<<1024, 256, 0, stream>>>(Wk, Whi, Wlo, W4);
        gemm8<2><<<gG, 512, SMEM_DYN, stream>>>(Xhi, Xlo, Whi, Wlo, bk, O, stab,
                                                PShi, PSlo, nullptr, nullptr, nullptr, nullptr, nullptr);
        // V chain
        convert_split<0><<<2048, 256, 0, stream>>>(value, Xhi, Xlo, X4);
        convert_split<1><<<1024, 256, 0, stream>>>(Wv, Whi, Wlo, W4);
        gemm8<0><<<gG, 512, SMEM_DYN, stream>>>(Xhi, Xlo, Whi, Wlo, bv, A, nullptr,
                                                nullptr, nullptr, nullptr, nullptr, nullptr, nullptr, nullptr);
        // kv
        kv_partial<<<gKV, 256, 0, stream>>>(O, A, stab, kvp, ksump);
        kv_reduce<<<nRed, 256, 0, stream>>>(kvp, ksump, kvM, ksum, kvThi, kvTlo);
        // Q chain: GEMM + fused favorp_q + qkv -> attn split-bf16 (A region)
        convert_split<0><<<2048, 256, 0, stream>>>(query, Xhi, Xlo, X4);
        convert_split<1><<<1024, 256, 0, stream>>>(Wq, Whi, Wlo, W4);
        gemm8<3><<<gG, 512, SMEM_DYN, stream>>>(Xhi, Xlo, Whi, Wlo, bq, nullptr, nullptr,
                                                PShi, PSlo, kvThi, kvTlo, ksum, AttnHi, AttnLo);
        // output GEMM
        convert_split<1><<<1024, 256, 0, stream>>>(Wo, Whi, Wlo, W4);
        gemm8<1><<<gG, 512, SMEM_DYN, stream>>>(AttnHi, AttnLo, Whi, Wlo, bo, O, nullptr,
                                                nullptr, nullptr, nullptr, nullptr, nullptr, nullptr, nullptr);
    } else {
        // fp32 fallback (round-2 proven path)
        dim3 gGemm(BN_ / 64, E_ / 64);
        lin_gemm<0,0><<<gGemm, 256, 0, stream>>>(key, Wk, bk, O);
        init_stab<<<1, 64, 0, stream>>>(stab);
        favorp_dash<0><<<gF, 256, 0, stream>>>(O, proj, stab);
        lin_gemm<0,0><<<gGemm, 256, 0, stream>>>(value, Wv, bv, A);
        kv_partial<<<gKV, 256, 0, stream>>>(O, A, stab, kvp, ksump);
        kv_reduce<<<nRed, 256, 0, stream>>>(kvp, ksump, kvM, ksum, kvThi, kvTlo);
        lin_gemm<0,0><<<gGemm, 256, 0, stream>>>(query, Wq, bq, O);
        favorp_dash<1><<<gF, 256, 0, stream>>>(O, proj, stab);
        qkv_attn<<<gF, 256, 0, stream>>>(O, kvM, ksum, A);
        lin_gemm<1,1><<<gGemm, 256, 0, stream>>>(A, Wo, bo, O);
    }
}